// Round 4
// baseline (428.190 us; speedup 1.0000x reference)
//
#include <hip/hip_runtime.h>
#include <hip/hip_bf16.h>
#include <math.h>

#define BB 2
#define SS 2048
#define DD 1024
#define HH 16
#define MLPD 4096

typedef __attribute__((ext_vector_type(8))) short bf16x8;
typedef __attribute__((ext_vector_type(4))) float f32x4;
typedef __attribute__((ext_vector_type(4))) unsigned short us4;

static __device__ __forceinline__ float fast_exp2(float x) {
#if __has_builtin(__builtin_amdgcn_exp2f)
  return __builtin_amdgcn_exp2f(x);
#else
  return exp2f(x);
#endif
}
static __device__ __forceinline__ float fast_rcp(float x) {
#if __has_builtin(__builtin_amdgcn_rcpf)
  return __builtin_amdgcn_rcpf(x);
#else
  return 1.0f / x;
#endif
}

static __device__ __forceinline__ unsigned short f2bf(float f) {
  union { float f; unsigned int u; } v; v.f = f;
  unsigned int r = v.u + 0x7fffu + ((v.u >> 16) & 1u);
  return (unsigned short)(r >> 16);
}
static __device__ __forceinline__ float bf2f(unsigned short b) {
  return __uint_as_float(((unsigned int)b) << 16);
}

// tanh-form GELU via exp2 (max |err| vs erf-GELU ~3e-4; bf16 noise is 100x)
static __device__ __forceinline__ float gelu_f(float x) {
  float u = x * x;
  float z = x * fmaf(u, 0.0713548162f, 1.59576912f);
  float e = fast_exp2(z * -1.44269504f);
  return x * fast_rcp(1.0f + e);
}

// XOR swizzle for 64B-row LDS tiles
static __device__ __forceinline__ int swz(int row) {
  return (row & 3) ^ ((row >> 2) & 3);
}

// async global->LDS, 16B per lane
static __device__ __forceinline__ void async16(const unsigned short* g, unsigned short* l) {
  __builtin_amdgcn_global_load_lds(
      (const __attribute__((address_space(1))) unsigned int*)g,
      (__attribute__((address_space(3))) unsigned int*)l, 16, 0, 0);
}

// ---------------------------------------------------------------------------
// fp32 [K][N] -> bf16 transposed [N][K], 32x32 LDS tiles
// ---------------------------------------------------------------------------
__global__ __launch_bounds__(256) void transpose_to_bf16(
    const float* __restrict__ src, unsigned short* __restrict__ dst,
    int K, int N) {
  __shared__ float tile[32][33];
  int t = threadIdx.x;
  int c = t & 31, rl = t >> 5;
  int bx = blockIdx.x, by = blockIdx.y;
#pragma unroll
  for (int i = 0; i < 4; ++i) {
    int row = rl * 4 + i;
    tile[row][c] = src[(size_t)(by * 32 + row) * N + bx * 32 + c];
  }
  __syncthreads();
#pragma unroll
  for (int i = 0; i < 4; ++i) {
    int n = rl * 4 + i;
    dst[(size_t)(bx * 32 + n) * K + by * 32 + c] = f2bf(tile[c][n]);
  }
}

// merged QKV weight transpose: grid.z picks wq/wk/wv
__global__ __launch_bounds__(256) void transpose_qkv(
    const float* __restrict__ wq, const float* __restrict__ wk,
    const float* __restrict__ wv, unsigned short* __restrict__ dst) {
  __shared__ float tile[32][33];
  const float* src = blockIdx.z == 0 ? wq : blockIdx.z == 1 ? wk : wv;
  unsigned short* d = dst + (size_t)blockIdx.z * 1024 * 1024;
  int t = threadIdx.x;
  int c = t & 31, rl = t >> 5;
  int bx = blockIdx.x, by = blockIdx.y;
#pragma unroll
  for (int i = 0; i < 4; ++i) {
    int row = rl * 4 + i;
    tile[row][c] = src[(size_t)(by * 32 + row) * DD + bx * 32 + c];
  }
  __syncthreads();
#pragma unroll
  for (int i = 0; i < 4; ++i) {
    int n = rl * 4 + i;
    d[(size_t)(bx * 32 + n) * DD + by * 32 + c] = f2bf(tile[c][n]);
  }
}

__global__ __launch_bounds__(256) void concat_bias(
    const float* __restrict__ bq, const float* __restrict__ bk,
    const float* __restrict__ bv, float* __restrict__ dst) {
  int i = blockIdx.x * 256 + threadIdx.x;
  if (i < 1024) dst[i] = bq[i];
  else if (i < 2048) dst[i] = bk[i - 1024];
  else if (i < 3072) dst[i] = bv[i - 2048];
}

// ---------------------------------------------------------------------------
// Mask pre-pack v3: same cmP layout as v2 but LDS-staged with float4 loads
// (v2's 128 scalar loads/thread cost ~13us). Layout:
//   cmP[b][qt(16)][wave(8)][kt(32)][lane(64)][16]
//   chunk[t*4+r] = (dis+cls)[qt*128+wave*16+(lane>>4)*4+r][kt*64+t*16+(lane&15)] * 8
// Block covers (b, qtO, waveO, ktg): 16 rows x 512 cols (8 kts).
// ---------------------------------------------------------------------------
__global__ __launch_bounds__(256) void mask_prep3(
    const float* __restrict__ dis, const float* __restrict__ cls,
    unsigned short* __restrict__ cmP) {
  __shared__ unsigned short sm[16][512];
  int qtO = blockIdx.x, waveO = blockIdx.y;
  int b = blockIdx.z >> 2, ktg = blockIdx.z & 3;
  int t = threadIdx.x;
  int row0 = qtO * 128 + waveO * 16;
  int col0 = ktg * 512;
  const float* db = dis + (size_t)b * SS * SS;
  const float* cb = cls + (size_t)b * SS * SS;
  // load 16 rows x 512 cols, vectorized
  int lrow = t >> 4, lcg = t & 15;
#pragma unroll
  for (int shot = 0; shot < 8; ++shot) {
    int cc = lcg * 4 + shot * 64;
    size_t idx = (size_t)(row0 + lrow) * SS + col0 + cc;
    float4 d4 = *(const float4*)(db + idx);
    float4 c4 = *(const float4*)(cb + idx);
    us4 o;
    o[0] = f2bf((d4.x + c4.x) * 8.0f);
    o[1] = f2bf((d4.y + c4.y) * 8.0f);
    o[2] = f2bf((d4.z + c4.z) * 8.0f);
    o[3] = f2bf((d4.w + c4.w) * 8.0f);
    *(us4*)&sm[lrow][cc] = o;
  }
  __syncthreads();
  // write chunks: thread handles ktL = t>>5, lanes lp*2, lp*2+1
  int ktL = t >> 5, lp = t & 31;
  unsigned short* ob =
      cmP + ((((size_t)b * 16 + qtO) * 8 + waveO) * 32 + ktg * 8 + ktL) * 64 * 16;
#pragma unroll
  for (int li = 0; li < 2; ++li) {
    int l = lp * 2 + li;
    int g = l >> 4, c16 = l & 15;
    short v[16];
#pragma unroll
    for (int t4 = 0; t4 < 4; ++t4)
#pragma unroll
      for (int r = 0; r < 4; ++r)
        v[t4 * 4 + r] = (short)sm[g * 4 + r][ktL * 64 + t4 * 16 + c16];
    unsigned short* o = ob + (size_t)l * 16;
    *(bf16x8*)(o) = *(bf16x8*)&v[0];
    *(bf16x8*)(o + 8) = *(bf16x8*)&v[8];
  }
}

// ---------------------------------------------------------------------------
// LayerNorm -> bf16 out
// ---------------------------------------------------------------------------
template <bool BF_IN, bool ADD>
__global__ __launch_bounds__(256) void ln_bf16(
    const void* __restrict__ in, const float* __restrict__ add,
    const float* __restrict__ g, const float* __restrict__ beta,
    unsigned short* __restrict__ out) {
  int row = blockIdx.x;
  int t = threadIdx.x;
  float x[4];
  if (BF_IN) {
    us4 b4 = *(const us4*)((const unsigned short*)in + (size_t)row * DD + t * 4);
#pragma unroll
    for (int i = 0; i < 4; ++i) x[i] = bf2f(b4[i]);
  } else {
    float4 f4 = *(const float4*)((const float*)in + (size_t)row * DD + t * 4);
    x[0] = f4.x; x[1] = f4.y; x[2] = f4.z; x[3] = f4.w;
  }
  if (ADD) {
    float4 a4 = *(const float4*)(add + (size_t)row * DD + t * 4);
    x[0] += a4.x; x[1] += a4.y; x[2] += a4.z; x[3] += a4.w;
  }
  float s1 = x[0] + x[1] + x[2] + x[3];
  float s2 = x[0] * x[0] + x[1] * x[1] + x[2] * x[2] + x[3] * x[3];
#pragma unroll
  for (int off = 32; off > 0; off >>= 1) {
    s1 += __shfl_down(s1, off);
    s2 += __shfl_down(s2, off);
  }
  __shared__ float sa[4], sb[4];
  int wid = t >> 6;
  if ((t & 63) == 0) { sa[wid] = s1; sb[wid] = s2; }
  __syncthreads();
  s1 = sa[0] + sa[1] + sa[2] + sa[3];
  s2 = sb[0] + sb[1] + sb[2] + sb[3];
  float mean = s1 * (1.0f / 1024.0f);
  float var = s2 * (1.0f / 1024.0f) - mean * mean;
  float rstd = rsqrtf(var + 1e-5f);
  float4 gv = *(const float4*)(g + t * 4);
  float4 bv = *(const float4*)(beta + t * 4);
  us4 o;
  o[0] = f2bf((x[0] - mean) * rstd * gv.x + bv.x);
  o[1] = f2bf((x[1] - mean) * rstd * gv.y + bv.y);
  o[2] = f2bf((x[2] - mean) * rstd * gv.z + bv.z);
  o[3] = f2bf((x[3] - mean) * rstd * gv.w + bv.w);
  *(us4*)(out + (size_t)row * DD + t * 4) = o;
}

// ---------------------------------------------------------------------------
// Legacy bf16 MFMA GEMM (128xBN tile, reg-prefetch). Kept for MLP2 (N=1024).
// ---------------------------------------------------------------------------
template <int BN, bool GELU, bool ADDSRC, bool OUT_BF16, bool SPLIT3>
__global__ __launch_bounds__(256) void gemm_bf16(
    const unsigned short* __restrict__ A, const unsigned short* __restrict__ BT,
    const float* __restrict__ bias, const unsigned short* __restrict__ addsrc,
    void* C0, void* C1, void* C2, int M, int N, int K) {
  constexpr int BJ = BN / 32;
  constexpr int BCH = BN / 64;
  __shared__ __align__(16) unsigned short As[128][32];
  __shared__ __align__(16) unsigned short Bs[BN][32];
  int tid = threadIdx.x;
  int wave = tid >> 6, lane = tid & 63;
  int g = lane >> 4, c16 = lane & 15;
  int m0 = blockIdx.y * 128, n0 = blockIdx.x * BN;
  int wm = (wave >> 1) * 64, wn = (wave & 1) * (BN / 2);
  int lrow = lane >> 2, lq = lane & 3;
  int dq = (lq ^ swz(lrow)) * 8;
  const unsigned short* aS = A + (size_t)(m0 + wave * 32 + lrow) * K + lq * 8;
  unsigned short* aD0 = &As[wave * 32 + lrow][dq];
  unsigned short* aD1 = &As[wave * 32 + 16 + lrow][dq];
  const unsigned short* bS = BT + (size_t)(n0 + wave * (BCH * 16) + lrow) * K + lq * 8;
  unsigned short* bD0 = &Bs[wave * (BCH * 16) + lrow][dq];
  unsigned short* bD1 = &Bs[(wave * (BCH * 16) + 16 + lrow) % BN][dq];
  int vA = (g ^ swz(c16)) * 8;
  const int KI = K / 32;
  const size_t rK = 16 * (size_t)K;

  bf16x8 a0a = *(const bf16x8*)(aS);
  bf16x8 a1a = *(const bf16x8*)(aS + rK);
  bf16x8 b0a = *(const bf16x8*)(bS);
  bf16x8 b1a;
  if constexpr (BCH == 2) b1a = *(const bf16x8*)(bS + rK);
  bf16x8 a0b = *(const bf16x8*)(aS + 32);
  bf16x8 a1b = *(const bf16x8*)(aS + rK + 32);
  bf16x8 b0b = *(const bf16x8*)(bS + 32);
  bf16x8 b1b;
  if constexpr (BCH == 2) b1b = *(const bf16x8*)(bS + rK + 32);

  f32x4 acc[4][BJ] = {};
  for (int kt = 0; kt < KI; kt += 2) {
    __syncthreads();
    *(bf16x8*)aD0 = a0a;
    *(bf16x8*)aD1 = a1a;
    *(bf16x8*)bD0 = b0a;
    if constexpr (BCH == 2) *(bf16x8*)bD1 = b1a;
    __syncthreads();
    if (kt + 2 < KI) {
      int ko = (kt + 2) * 32;
      a0a = *(const bf16x8*)(aS + ko);
      a1a = *(const bf16x8*)(aS + rK + ko);
      b0a = *(const bf16x8*)(bS + ko);
      if constexpr (BCH == 2) b1a = *(const bf16x8*)(bS + rK + ko);
    }
    {
      bf16x8 a[4], b[BJ];
#pragma unroll
      for (int i = 0; i < 4; ++i) a[i] = *(const bf16x8*)&As[wm + i * 16 + c16][vA];
#pragma unroll
      for (int j = 0; j < BJ; ++j) b[j] = *(const bf16x8*)&Bs[wn + j * 16 + c16][vA];
#pragma unroll
      for (int i = 0; i < 4; ++i)
#pragma unroll
        for (int j = 0; j < BJ; ++j)
          acc[i][j] = __builtin_amdgcn_mfma_f32_16x16x32_bf16(a[i], b[j], acc[i][j], 0, 0, 0);
    }
    __syncthreads();
    *(bf16x8*)aD0 = a0b;
    *(bf16x8*)aD1 = a1b;
    *(bf16x8*)bD0 = b0b;
    if constexpr (BCH == 2) *(bf16x8*)bD1 = b1b;
    __syncthreads();
    if (kt + 3 < KI) {
      int ko = (kt + 3) * 32;
      a0b = *(const bf16x8*)(aS + ko);
      a1b = *(const bf16x8*)(aS + rK + ko);
      b0b = *(const bf16x8*)(bS + ko);
      if constexpr (BCH == 2) b1b = *(const bf16x8*)(bS + rK + ko);
    }
    {
      bf16x8 a[4], b[BJ];
#pragma unroll
      for (int i = 0; i < 4; ++i) a[i] = *(const bf16x8*)&As[wm + i * 16 + c16][vA];
#pragma unroll
      for (int j = 0; j < BJ; ++j) b[j] = *(const bf16x8*)&Bs[wn + j * 16 + c16][vA];
#pragma unroll
      for (int i = 0; i < 4; ++i)
#pragma unroll
        for (int j = 0; j < BJ; ++j)
          acc[i][j] = __builtin_amdgcn_mfma_f32_16x16x32_bf16(a[i], b[j], acc[i][j], 0, 0, 0);
    }
  }
  unsigned short* dstb = nullptr;
  int lc0 = 0;
  if (SPLIT3) {
    int which = n0 >> 10;
    dstb = (unsigned short*)(which == 0 ? C0 : which == 1 ? C1 : C2);
    lc0 = n0 & 1023;
  }
#pragma unroll
  for (int j = 0; j < BJ; ++j) {
    int coff = wn + j * 16 + c16;
    float bj = bias[n0 + coff];
#pragma unroll
    for (int i = 0; i < 4; ++i) {
#pragma unroll
      for (int r = 0; r < 4; ++r) {
        int row = m0 + wm + i * 16 + g * 4 + r;
        float cval = acc[i][j][r] + bj;
        if (GELU) cval = gelu_f(cval);
        if (ADDSRC) cval += bf2f(addsrc[(size_t)row * N + n0 + coff]);
        if (SPLIT3) {
          dstb[(size_t)row * 1024 + lc0 + coff] = f2bf(cval);
        } else if (OUT_BF16) {
          ((unsigned short*)C0)[(size_t)row * N + n0 + coff] = f2bf(cval);
        } else {
          ((float*)C0)[(size_t)row * N + n0 + coff] = cval;
        }
      }
    }
  }
}

// ---------------------------------------------------------------------------
// 256x256 8-phase bf16 GEMM v2 (snake order + reg fragment reuse), now with
// bijective XCD-aware block swizzle (T1; nwg%8==0 for both grids).
// ---------------------------------------------------------------------------
#define VMW(n) asm volatile("s_waitcnt vmcnt(" #n ")" ::: "memory")
#define BARX() do { asm volatile("" ::: "memory"); \
                    __builtin_amdgcn_s_barrier(); \
                    asm volatile("" ::: "memory"); } while (0)

template <bool GELU, bool SPLIT3>
__global__ __launch_bounds__(512, 2) void gemm256(
    const unsigned short* __restrict__ A, const unsigned short* __restrict__ BT,
    const float* __restrict__ bias, void* C0, void* C1, void* C2,
    int N, int K) {
  __shared__ __align__(16) char lds[2][2][2][16384];
  int tid = threadIdx.x;
  int lane = tid & 63, w = tid >> 6;
  int g = lane >> 4, c16 = lane & 15;
  int wm16 = (w >> 2) << 4;
  int wn16 = (w & 3) << 4;
  // XCD swizzle: hardware XCD = wgid%8; give each XCD a contiguous tile chunk
  int nwg = gridDim.x * gridDim.y;
  int wg = blockIdx.y * gridDim.x + blockIdx.x;
  int cpx = nwg >> 3;
  int sw = (wg & 7) * cpx + (wg >> 3);
  int bx = sw % gridDim.x, by = sw / gridDim.x;
  int m0 = by << 8, n0 = bx << 8;

  int st0 = tid >> 6, ci0 = tid & 63;
  int cp0 = ci0 ^ (((ci0 >> 5) & 1) << 1);
  int sr0 = ((st0 >> 1) << 4) + (cp0 >> 2);
  int sk0 = ((st0 & 1) << 5) + ((cp0 & 3) << 3);
  size_t soff = (size_t)sr0 * K + sk0;

  auto stage = [&](int op, int h, int tt, int d) {
    const unsigned short* base = (op == 0 ? A : BT);
    int row0 = (op == 0 ? m0 : n0) + (h << 7);
    const unsigned short* src = base + (size_t)row0 * K + (tt << 6) + soff;
    unsigned short* dst = (unsigned short*)&lds[op][d][h][tid * 16];
    async16(src, dst);
    async16(src + ((size_t)K << 6), dst + 4096);
  };

  auto foff = [&](int r, int ke) -> int {
    int stt = ((r >> 4) << 1) + (ke >> 5);
    int loc = ((r & 15) << 6) + ((ke & 31) << 1);
    return (stt << 10) + (loc ^ (((r >> 3) & 1) << 5));
  };
  int offA[4][2], offB[2][2];
#pragma unroll
  for (int ii = 0; ii < 4; ++ii)
#pragma unroll
    for (int ks = 0; ks < 2; ++ks)
      offA[ii][ks] = foff(ii * 32 + wm16 + c16, ks * 32 + g * 8);
#pragma unroll
  for (int jj = 0; jj < 2; ++jj)
#pragma unroll
    for (int ks = 0; ks < 2; ++ks)
      offB[jj][ks] = foff(jj * 64 + wn16 + c16, ks * 32 + g * 8);

  f32x4 acc[8][4] = {};

#define MFMA_Q(IH, JH, AF, BF) do {                                           \
    __builtin_amdgcn_s_setprio(1);                                            \
    _Pragma("unroll") for (int ii = 0; ii < 4; ++ii)                          \
      _Pragma("unroll") for (int jj = 0; jj < 2; ++jj) {                      \
        acc[(IH)*4+ii][(JH)*2+jj] = __builtin_amdgcn_mfma_f32_16x16x32_bf16(  \
            AF[ii][0], BF[jj][0], acc[(IH)*4+ii][(JH)*2+jj], 0, 0, 0);        \
        acc[(IH)*4+ii][(JH)*2+jj] = __builtin_amdgcn_mfma_f32_16x16x32_bf16(  \
            AF[ii][1], BF[jj][1], acc[(IH)*4+ii][(JH)*2+jj], 0, 0, 0);        \
      }                                                                       \
    __builtin_amdgcn_s_setprio(0);                                            \
  } while (0)

  stage(0, 0, 0, 0);
  stage(1, 0, 0, 0);
  stage(0, 1, 0, 0);
  stage(1, 1, 0, 0);
  VMW(4);
  BARX();

  const int KT = K >> 6;
  for (int kt = 0; kt < KT; ++kt) {
    int d = kt & 1, dn = d ^ 1;
    int t1 = kt + 1 < KT ? kt + 1 : KT - 1;
    const char* pd = &lds[0][d][0][0];
    bf16x8 A0f[4][2], A1f[4][2], Bf[2][2];

#pragma unroll
    for (int ii = 0; ii < 4; ++ii)
#pragma unroll
      for (int ks = 0; ks < 2; ++ks)
        A0f[ii][ks] = *(const bf16x8*)(pd + offA[ii][ks]);
#pragma unroll
    for (int jj = 0; jj < 2; ++jj)
#pragma unroll
      for (int ks = 0; ks < 2; ++ks)
        Bf[jj][ks] = *(const bf16x8*)(pd + 65536 + offB[jj][ks]);
    stage(0, 0, t1, dn);
    VMW(4);
    BARX();
    MFMA_Q(0, 0, A0f, Bf);
    BARX();

#pragma unroll
    for (int ii = 0; ii < 4; ++ii)
#pragma unroll
      for (int ks = 0; ks < 2; ++ks)
        A1f[ii][ks] = *(const bf16x8*)(pd + 16384 + offA[ii][ks]);
    stage(1, 0, t1, dn);
    VMW(4);
    BARX();
    MFMA_Q(1, 0, A1f, Bf);
    BARX();

#pragma unroll
    for (int jj = 0; jj < 2; ++jj)
#pragma unroll
      for (int ks = 0; ks < 2; ++ks)
        Bf[jj][ks] = *(const bf16x8*)(pd + 81920 + offB[jj][ks]);
    stage(0, 1, t1, dn);
    VMW(4);
    BARX();
    MFMA_Q(1, 1, A1f, Bf);
    BARX();

    stage(1, 1, t1, dn);
    VMW(4);
    BARX();
    MFMA_Q(0, 1, A0f, Bf);
    BARX();
  }
#undef MFMA_Q
  VMW(0);

  unsigned short* dstb = nullptr;
  int lc0 = 0;
  if (SPLIT3) {
    int which = n0 >> 10;
    dstb = (unsigned short*)(which == 0 ? C0 : which == 1 ? C1 : C2);
    lc0 = n0 & 1023;
  }
#pragma unroll
  for (int i = 0; i < 8; ++i) {
#pragma unroll
    for (int j = 0; j < 4; ++j) {
      int row_b = m0 + ((i >> 2) << 7) + ((i & 3) << 5) + wm16 + (g << 2);
      int colp = ((j >> 1) << 7) + ((j & 1) << 6) + wn16 + c16;
      float bj = bias[n0 + colp];
#pragma unroll
      for (int r = 0; r < 4; ++r) {
        float cv = acc[i][j][r] + bj;
        if (GELU) cv = gelu_f(cv);
        int row = row_b + r;
        if (SPLIT3) {
          dstb[(size_t)row * 1024 + lc0 + colp] = f2bf(cv);
        } else {
          ((unsigned short*)C0)[(size_t)row * N + n0 + colp] = f2bf(cv);
        }
      }
    }
  }
}

// ---------------------------------------------------------------------------
// MFMA flash attention v4: 64 q-rows / 4 waves per block, head-split into
// two dispatches (hbase) so GEMM dispatches surface in rocprof top-5.
// Same math as v3 (mask pre-packed in C-frag layout initializes QK acc).
// ---------------------------------------------------------------------------
__global__ __launch_bounds__(256) void attn_mfma4(
    const unsigned short* __restrict__ q, const unsigned short* __restrict__ k,
    const unsigned short* __restrict__ v, const unsigned short* __restrict__ cmP,
    unsigned short* __restrict__ outO, int hbase) {
  __shared__ __align__(16) unsigned short Ks[2][64][32];
  __shared__ __align__(16) unsigned short Vt[64][72];
  __shared__ __align__(16) unsigned short Ps[64][72];
  int tid = threadIdx.x;
  int wave = tid >> 6, lane = tid & 63;
  int g = lane >> 4, c16 = lane & 15;
  int qt = blockIdx.x;            // 0..31 (64-row tiles)
  int h = hbase + blockIdx.y;     // 8 heads per dispatch
  int b = blockIdx.z;
  int s0 = qt * 64;
  int wr = wave * 16;             // 0..48
  size_t headoff = (size_t)b * SS * DD + (size_t)h * SS * 64;
  const unsigned short* qb = q + headoff;
  const unsigned short* kb = k + headoff;
  const unsigned short* vb = v + headoff;
  int waveO = (qt & 1) * 4 + wave;  // old 8-wave index in cmP layout
  const unsigned short* csrc =
      cmP + ((((size_t)b * 16 + (qt >> 1)) * 8 + waveO) * 32 * 64 + lane) * 16;

  // K staging: 256 thr, thread covers row kkey (0..63), two 8-elem segs
  int kkey = tid >> 2, lq2 = tid & 3;
  int ksg0 = lq2 * 2, ksg1 = lq2 * 2 + 1;
  unsigned short* kdst0 = &Ks[ksg0 >> 2][kkey][((ksg0 & 3) ^ swz(kkey)) * 8];
  unsigned short* kdst1 = &Ks[ksg1 >> 2][kkey][((ksg1 & 3) ^ swz(kkey)) * 8];
  const unsigned short* ksrc = kb + (size_t)kkey * 64 + ksg0 * 8;
  // V staging: lane = key, wave covers hd wave*16..+16 (two bf16x8)
  const unsigned short* vsrc = vb + (size_t)lane * 64 + wave * 16;
  int vK = (g ^ swz(c16)) * 8;

  bf16x8 qf0, qf1;
  {
    size_t qrow = (size_t)(s0 + wr + c16) * 64;
    qf0 = *(const bf16x8*)(qb + qrow + g * 8);
    qf1 = *(const bf16x8*)(qb + qrow + 32 + g * 8);
  }
  bf16x8 ones;
#pragma unroll
  for (int j = 0; j < 8; ++j) ones[j] = (short)0x3F80;
  f32x4 o[4] = {};
  f32x4 ol = {};
  const float scale2 = 0.18033688f;  // 0.125*log2(e)

  bf16x8 kregA = *(const bf16x8*)(ksrc);
  bf16x8 kregB = *(const bf16x8*)(ksrc + 8);
  bf16x8 vregA = *(const bf16x8*)(vsrc);
  bf16x8 vregB = *(const bf16x8*)(vsrc + 8);
  bf16x8 cmA = *(const bf16x8*)(csrc);
  bf16x8 cmB = *(const bf16x8*)(csrc + 8);

  for (int kt = 0; kt < 32; ++kt) {
    __syncthreads();
    *(bf16x8*)kdst0 = kregA;
    *(bf16x8*)kdst1 = kregB;
#pragma unroll
    for (int j = 0; j < 8; ++j) {
      Vt[wave * 16 + j][lane] = (unsigned short)vregA[j];
      Vt[wave * 16 + 8 + j][lane] = (unsigned short)vregB[j];
    }
    __syncthreads();

    int ktn = kt + 1 < 32 ? kt + 1 : 31;
    bf16x8 kregAN = *(const bf16x8*)(ksrc + (size_t)ktn * 4096);
    bf16x8 kregBN = *(const bf16x8*)(ksrc + (size_t)ktn * 4096 + 8);
    bf16x8 vregAN = *(const bf16x8*)(vsrc + (size_t)ktn * 4096);
    bf16x8 vregBN = *(const bf16x8*)(vsrc + (size_t)ktn * 4096 + 8);
    bf16x8 cmAN = *(const bf16x8*)(csrc + (size_t)ktn * 1024);
    bf16x8 cmBN = *(const bf16x8*)(csrc + (size_t)ktn * 1024 + 8);

    f32x4 s[4];
#pragma unroll
    for (int r = 0; r < 4; ++r) {
      s[0][r] = bf2f((unsigned short)cmA[r]);
      s[1][r] = bf2f((unsigned short)cmA[4 + r]);
      s[2][r] = bf2f((unsigned short)cmB[r]);
      s[3][r] = bf2f((unsigned short)cmB[4 + r]);
    }
#pragma unroll
    for (int t = 0; t < 4; ++t) {
      bf16x8 b0 = *(const bf16x8*)&Ks[0][t * 16 + c16][vK];
      bf16x8 b1 = *(const bf16x8*)&Ks[1][t * 16 + c16][vK];
      s[t] = __builtin_amdgcn_mfma_f32_16x16x32_bf16(qf0, b0, s[t], 0, 0, 0);
      s[t] = __builtin_amdgcn_mfma_f32_16x16x32_bf16(qf1, b1, s[t], 0, 0, 0);
    }
#pragma unroll
    for (int t = 0; t < 4; ++t)
#pragma unroll
      for (int r = 0; r < 4; ++r) {
        float p = fast_exp2(s[t][r] * scale2);
        Ps[wr + g * 4 + r][t * 16 + c16] = (unsigned short)(__float_as_uint(p) >> 16);
      }
#pragma unroll
    for (int ks = 0; ks < 2; ++ks) {
      bf16x8 pa = *(const bf16x8*)&Ps[wr + c16][ks * 32 + g * 8];
#pragma unroll
      for (int t2 = 0; t2 < 4; ++t2) {
        bf16x8 vb8 = *(const bf16x8*)&Vt[t2 * 16 + c16][ks * 32 + g * 8];
        o[t2] = __builtin_amdgcn_mfma_f32_16x16x32_bf16(pa, vb8, o[t2], 0, 0, 0);
      }
      ol = __builtin_amdgcn_mfma_f32_16x16x32_bf16(pa, ones, ol, 0, 0, 0);
    }
    kregA = kregAN; kregB = kregBN;
    vregA = vregAN; vregB = vregBN;
    cmA = cmAN; cmB = cmBN;
  }
  float inv[4];
#pragma unroll
  for (int r = 0; r < 4; ++r) inv[r] = fast_rcp(ol[r]);
#pragma unroll
  for (int t2 = 0; t2 < 4; ++t2)
#pragma unroll
    for (int r = 0; r < 4; ++r) {
      int srow = s0 + wr + g * 4 + r;
      outO[headoff + (size_t)srow * 64 + t2 * 16 + c16] = f2bf(o[t2][r] * inv[r]);
    }
}

// ---------------------------------------------------------------------------
extern "C" void kernel_launch(void* const* d_in, const int* in_sizes, int n_in,
                              void* d_out, int out_size, void* d_ws, size_t ws_size,
                              hipStream_t stream) {
  const float* x    = (const float*)d_in[0];
  const float* dis  = (const float*)d_in[1];
  const float* cls  = (const float*)d_in[2];
  const float* wq   = (const float*)d_in[3];
  const float* bq   = (const float*)d_in[4];
  const float* wk   = (const float*)d_in[5];
  const float* bk   = (const float*)d_in[6];
  const float* wv   = (const float*)d_in[7];
  const float* bv   = (const float*)d_in[8];
  const float* ln1g = (const float*)d_in[9];
  const float* ln1b = (const float*)d_in[10];
  const float* ln2g = (const float*)d_in[11];
  const float* ln2b = (const float*)d_in[12];
  const float* w1   = (const float*)d_in[13];
  const float* b1   = (const float*)d_in[14];
  const float* w2   = (const float*)d_in[15];
  const float* b2   = (const float*)d_in[16];
  float* out = (float*)d_out;
  char* ws = (char*)d_ws;

  unsigned short* qkvwT = (unsigned short*)(ws + 0);           // 6 MB
  unsigned short* w1T   = (unsigned short*)(ws + 6291456);     // 8 MB
  unsigned short* w2T   = (unsigned short*)(ws + 14680064);    // 8 MB
  float*          qkvb  = (float*)(ws + 23068672);             // 12 KB
  unsigned short* r1    = (unsigned short*)(ws + 23134208);    // 8 MB: h1 -> attnO
  unsigned short* qbuf  = (unsigned short*)(ws + 31522816);    // 8 MB
  unsigned short* kbuf  = (unsigned short*)(ws + 39911424);    // 8 MB
  unsigned short* vbuf  = (unsigned short*)(ws + 48300032);    // 8 MB
  unsigned short* h2    = (unsigned short*)(ws + 56688640);    // 8 MB
  unsigned short* cmP   = (unsigned short*)(ws + 65077248);    // 16.78 MB
  unsigned short* mm    = (unsigned short*)(ws + 23134208);    // 32 MB overlays r1/q/k/v
  unsigned short* h1 = r1;
  unsigned short* attnO = r1;

  const int rows = BB * SS;  // 4096

  transpose_qkv<<<dim3(DD / 32, DD / 32, 3), 256, 0, stream>>>(wq, wk, wv, qkvwT);
  transpose_to_bf16<<<dim3(MLPD / 32, DD / 32), 256, 0, stream>>>(w1, w1T, DD, MLPD);
  transpose_to_bf16<<<dim3(DD / 32, MLPD / 32), 256, 0, stream>>>(w2, w2T, MLPD, DD);
  concat_bias<<<12, 256, 0, stream>>>(bq, bk, bv, qkvb);
  mask_prep3<<<dim3(16, 8, 8), 256, 0, stream>>>(dis, cls, cmP);

  ln_bf16<false, false><<<rows, 256, 0, stream>>>(x, nullptr, ln1g, ln1b, h1);

  // QKV: 256x256 8-phase v2 + XCD swizzle, SPLIT3 epilogue (192 blocks)
  gemm256<false, true><<<dim3(3072 / 256, rows / 256), 512, 0, stream>>>(
      h1, qkvwT, qkvb, qbuf, kbuf, vbuf, 3072, DD);

  // attn split into 2 head-halves (diagnostic: surfaces GEMM rows in top-5)
  attn_mfma4<<<dim3(SS / 64, HH / 2, BB), 256, 0, stream>>>(
      qbuf, kbuf, vbuf, cmP, attnO, 0);
  attn_mfma4<<<dim3(SS / 64, HH / 2, BB), 256, 0, stream>>>(
      qbuf, kbuf, vbuf, cmP, attnO, 8);

  ln_bf16<true, true><<<rows, 256, 0, stream>>>(attnO, x, ln2g, ln2b, h2);

  // MLP1: 256x256 8-phase v2 + XCD swizzle + GELU (256 blocks)
  gemm256<true, false><<<dim3(MLPD / 256, rows / 256), 512, 0, stream>>>(
      h2, w1T, b1, mm, nullptr, nullptr, MLPD, DD);

  // MLP2 (N=1024): legacy 128x64 path
  gemm_bf16<64, false, true, false, false><<<dim3(DD / 64, rows / 128), 256, 0, stream>>>(
      mm, w2T, b2, h2, out, nullptr, nullptr, rows, DD, MLPD);
}

// Round 5
// 389.787 us; speedup vs baseline: 1.0985x; 1.0985x over previous
//
#include <hip/hip_runtime.h>
#include <hip/hip_bf16.h>
#include <math.h>

#define BB 2
#define SS 2048
#define DD 1024
#define HH 16
#define MLPD 4096

typedef __attribute__((ext_vector_type(8))) short bf16x8;
typedef __attribute__((ext_vector_type(4))) float f32x4;
typedef __attribute__((ext_vector_type(4))) unsigned short us4;

static __device__ __forceinline__ float fast_exp2(float x) {
#if __has_builtin(__builtin_amdgcn_exp2f)
  return __builtin_amdgcn_exp2f(x);
#else
  return exp2f(x);
#endif
}
static __device__ __forceinline__ float fast_rcp(float x) {
#if __has_builtin(__builtin_amdgcn_rcpf)
  return __builtin_amdgcn_rcpf(x);
#else
  return 1.0f / x;
#endif
}

static __device__ __forceinline__ unsigned short f2bf(float f) {
  union { float f; unsigned int u; } v; v.f = f;
  unsigned int r = v.u + 0x7fffu + ((v.u >> 16) & 1u);
  return (unsigned short)(r >> 16);
}
static __device__ __forceinline__ float bf2f(unsigned short b) {
  return __uint_as_float(((unsigned int)b) << 16);
}

// tanh-form GELU via exp2 (max |err| vs erf-GELU ~3e-4; bf16 noise is 100x)
static __device__ __forceinline__ float gelu_f(float x) {
  float u = x * x;
  float z = x * fmaf(u, 0.0713548162f, 1.59576912f);
  float e = fast_exp2(z * -1.44269504f);
  return x * fast_rcp(1.0f + e);
}

// XOR swizzle for 64B-row LDS tiles
static __device__ __forceinline__ int swz(int row) {
  return (row & 3) ^ ((row >> 2) & 3);
}

// async global->LDS, 16B per lane
static __device__ __forceinline__ void async16(const unsigned short* g, unsigned short* l) {
  __builtin_amdgcn_global_load_lds(
      (const __attribute__((address_space(1))) unsigned int*)g,
      (__attribute__((address_space(3))) unsigned int*)l, 16, 0, 0);
}

// ---------------------------------------------------------------------------
// fp32 [K][N] -> bf16 transposed [N][K], 32x32 LDS tiles
// ---------------------------------------------------------------------------
__global__ __launch_bounds__(256) void transpose_to_bf16(
    const float* __restrict__ src, unsigned short* __restrict__ dst,
    int K, int N) {
  __shared__ float tile[32][33];
  int t = threadIdx.x;
  int c = t & 31, rl = t >> 5;
  int bx = blockIdx.x, by = blockIdx.y;
#pragma unroll
  for (int i = 0; i < 4; ++i) {
    int row = rl * 4 + i;
    tile[row][c] = src[(size_t)(by * 32 + row) * N + bx * 32 + c];
  }
  __syncthreads();
#pragma unroll
  for (int i = 0; i < 4; ++i) {
    int n = rl * 4 + i;
    dst[(size_t)(bx * 32 + n) * K + by * 32 + c] = f2bf(tile[c][n]);
  }
}

// merged QKV weight transpose: grid.z picks wq/wk/wv
__global__ __launch_bounds__(256) void transpose_qkv(
    const float* __restrict__ wq, const float* __restrict__ wk,
    const float* __restrict__ wv, unsigned short* __restrict__ dst) {
  __shared__ float tile[32][33];
  const float* src = blockIdx.z == 0 ? wq : blockIdx.z == 1 ? wk : wv;
  unsigned short* d = dst + (size_t)blockIdx.z * 1024 * 1024;
  int t = threadIdx.x;
  int c = t & 31, rl = t >> 5;
  int bx = blockIdx.x, by = blockIdx.y;
#pragma unroll
  for (int i = 0; i < 4; ++i) {
    int row = rl * 4 + i;
    tile[row][c] = src[(size_t)(by * 32 + row) * DD + bx * 32 + c];
  }
  __syncthreads();
#pragma unroll
  for (int i = 0; i < 4; ++i) {
    int n = rl * 4 + i;
    d[(size_t)(bx * 32 + n) * DD + by * 32 + c] = f2bf(tile[c][n]);
  }
}

__global__ __launch_bounds__(256) void concat_bias(
    const float* __restrict__ bq, const float* __restrict__ bk,
    const float* __restrict__ bv, float* __restrict__ dst) {
  int i = blockIdx.x * 256 + threadIdx.x;
  if (i < 1024) dst[i] = bq[i];
  else if (i < 2048) dst[i] = bk[i - 1024];
  else if (i < 3072) dst[i] = bv[i - 2048];
}

// ---------------------------------------------------------------------------
// Mask pre-pack v3 (LDS-staged, float4 loads). Layout:
//   cmP[b][qt(16)][wave(8)][kt(32)][lane(64)][16]
//   chunk[t*4+r] = (dis+cls)[qt*128+wave*16+(lane>>4)*4+r][kt*64+t*16+(lane&15)] * 8
// ---------------------------------------------------------------------------
__global__ __launch_bounds__(256) void mask_prep3(
    const float* __restrict__ dis, const float* __restrict__ cls,
    unsigned short* __restrict__ cmP) {
  __shared__ unsigned short sm[16][512];
  int qtO = blockIdx.x, waveO = blockIdx.y;
  int b = blockIdx.z >> 2, ktg = blockIdx.z & 3;
  int t = threadIdx.x;
  int row0 = qtO * 128 + waveO * 16;
  int col0 = ktg * 512;
  const float* db = dis + (size_t)b * SS * SS;
  const float* cb = cls + (size_t)b * SS * SS;
  int lrow = t >> 4, lcg = t & 15;
#pragma unroll
  for (int shot = 0; shot < 8; ++shot) {
    int cc = lcg * 4 + shot * 64;
    size_t idx = (size_t)(row0 + lrow) * SS + col0 + cc;
    float4 d4 = *(const float4*)(db + idx);
    float4 c4 = *(const float4*)(cb + idx);
    us4 o;
    o[0] = f2bf((d4.x + c4.x) * 8.0f);
    o[1] = f2bf((d4.y + c4.y) * 8.0f);
    o[2] = f2bf((d4.z + c4.z) * 8.0f);
    o[3] = f2bf((d4.w + c4.w) * 8.0f);
    *(us4*)&sm[lrow][cc] = o;
  }
  __syncthreads();
  int ktL = t >> 5, lp = t & 31;
  unsigned short* ob =
      cmP + ((((size_t)b * 16 + qtO) * 8 + waveO) * 32 + ktg * 8 + ktL) * 64 * 16;
#pragma unroll
  for (int li = 0; li < 2; ++li) {
    int l = lp * 2 + li;
    int g = l >> 4, c16 = l & 15;
    short v[16];
#pragma unroll
    for (int t4 = 0; t4 < 4; ++t4)
#pragma unroll
      for (int r = 0; r < 4; ++r)
        v[t4 * 4 + r] = (short)sm[g * 4 + r][ktL * 64 + t4 * 16 + c16];
    unsigned short* o = ob + (size_t)l * 16;
    *(bf16x8*)(o) = *(bf16x8*)&v[0];
    *(bf16x8*)(o + 8) = *(bf16x8*)&v[8];
  }
}

// ---------------------------------------------------------------------------
// LayerNorm -> bf16 out
// ---------------------------------------------------------------------------
template <bool BF_IN, bool ADD>
__global__ __launch_bounds__(256) void ln_bf16(
    const void* __restrict__ in, const float* __restrict__ add,
    const float* __restrict__ g, const float* __restrict__ beta,
    unsigned short* __restrict__ out) {
  int row = blockIdx.x;
  int t = threadIdx.x;
  float x[4];
  if (BF_IN) {
    us4 b4 = *(const us4*)((const unsigned short*)in + (size_t)row * DD + t * 4);
#pragma unroll
    for (int i = 0; i < 4; ++i) x[i] = bf2f(b4[i]);
  } else {
    float4 f4 = *(const float4*)((const float*)in + (size_t)row * DD + t * 4);
    x[0] = f4.x; x[1] = f4.y; x[2] = f4.z; x[3] = f4.w;
  }
  if (ADD) {
    float4 a4 = *(const float4*)(add + (size_t)row * DD + t * 4);
    x[0] += a4.x; x[1] += a4.y; x[2] += a4.z; x[3] += a4.w;
  }
  float s1 = x[0] + x[1] + x[2] + x[3];
  float s2 = x[0] * x[0] + x[1] * x[1] + x[2] * x[2] + x[3] * x[3];
#pragma unroll
  for (int off = 32; off > 0; off >>= 1) {
    s1 += __shfl_down(s1, off);
    s2 += __shfl_down(s2, off);
  }
  __shared__ float sa[4], sb[4];
  int wid = t >> 6;
  if ((t & 63) == 0) { sa[wid] = s1; sb[wid] = s2; }
  __syncthreads();
  s1 = sa[0] + sa[1] + sa[2] + sa[3];
  s2 = sb[0] + sb[1] + sb[2] + sb[3];
  float mean = s1 * (1.0f / 1024.0f);
  float var = s2 * (1.0f / 1024.0f) - mean * mean;
  float rstd = rsqrtf(var + 1e-5f);
  float4 gv = *(const float4*)(g + t * 4);
  float4 bv = *(const float4*)(beta + t * 4);
  us4 o;
  o[0] = f2bf((x[0] - mean) * rstd * gv.x + bv.x);
  o[1] = f2bf((x[1] - mean) * rstd * gv.y + bv.y);
  o[2] = f2bf((x[2] - mean) * rstd * gv.z + bv.z);
  o[3] = f2bf((x[3] - mean) * rstd * gv.w + bv.w);
  *(us4*)(out + (size_t)row * DD + t * 4) = o;
}

// ---------------------------------------------------------------------------
// Legacy bf16 MFMA GEMM (128xBN tile, reg-prefetch) for MLP2 (N=1024),
// now with XCD-contiguous block swizzle: blocks sharing an A-panel (same by)
// land on the SAME XCD/L2 (r4 counters: FETCH 139MB vs 48MB unique = 3.5x
// amplification from round-robin XCD scatter).
// ---------------------------------------------------------------------------
template <int BN, bool GELU, bool ADDSRC, bool OUT_BF16, bool SPLIT3>
__global__ __launch_bounds__(256) void gemm_bf16(
    const unsigned short* __restrict__ A, const unsigned short* __restrict__ BT,
    const float* __restrict__ bias, const unsigned short* __restrict__ addsrc,
    void* C0, void* C1, void* C2, int M, int N, int K) {
  constexpr int BJ = BN / 32;
  constexpr int BCH = BN / 64;
  __shared__ __align__(16) unsigned short As[128][32];
  __shared__ __align__(16) unsigned short Bs[BN][32];
  int tid = threadIdx.x;
  int wave = tid >> 6, lane = tid & 63;
  int g = lane >> 4, c16 = lane & 15;
  // XCD swizzle (requires nwg % 8 == 0): XCD c computes a contiguous chunk
  // of x-fastest tile ids -> same-by blocks share one L2.
  int nwg = gridDim.x * gridDim.y;
  int wg = blockIdx.y * gridDim.x + blockIdx.x;
  int cpx = nwg >> 3;
  int sw = (wg & 7) * cpx + (wg >> 3);
  int bxs = sw % gridDim.x, bys = sw / gridDim.x;
  int m0 = bys * 128, n0 = bxs * BN;
  int wm = (wave >> 1) * 64, wn = (wave & 1) * (BN / 2);
  int lrow = lane >> 2, lq = lane & 3;
  int dq = (lq ^ swz(lrow)) * 8;
  const unsigned short* aS = A + (size_t)(m0 + wave * 32 + lrow) * K + lq * 8;
  unsigned short* aD0 = &As[wave * 32 + lrow][dq];
  unsigned short* aD1 = &As[wave * 32 + 16 + lrow][dq];
  const unsigned short* bS = BT + (size_t)(n0 + wave * (BCH * 16) + lrow) * K + lq * 8;
  unsigned short* bD0 = &Bs[wave * (BCH * 16) + lrow][dq];
  unsigned short* bD1 = &Bs[(wave * (BCH * 16) + 16 + lrow) % BN][dq];
  int vA = (g ^ swz(c16)) * 8;
  const int KI = K / 32;
  const size_t rK = 16 * (size_t)K;

  bf16x8 a0a = *(const bf16x8*)(aS);
  bf16x8 a1a = *(const bf16x8*)(aS + rK);
  bf16x8 b0a = *(const bf16x8*)(bS);
  bf16x8 b1a;
  if constexpr (BCH == 2) b1a = *(const bf16x8*)(bS + rK);
  bf16x8 a0b = *(const bf16x8*)(aS + 32);
  bf16x8 a1b = *(const bf16x8*)(aS + rK + 32);
  bf16x8 b0b = *(const bf16x8*)(bS + 32);
  bf16x8 b1b;
  if constexpr (BCH == 2) b1b = *(const bf16x8*)(bS + rK + 32);

  f32x4 acc[4][BJ] = {};
  for (int kt = 0; kt < KI; kt += 2) {
    __syncthreads();
    *(bf16x8*)aD0 = a0a;
    *(bf16x8*)aD1 = a1a;
    *(bf16x8*)bD0 = b0a;
    if constexpr (BCH == 2) *(bf16x8*)bD1 = b1a;
    __syncthreads();
    if (kt + 2 < KI) {
      int ko = (kt + 2) * 32;
      a0a = *(const bf16x8*)(aS + ko);
      a1a = *(const bf16x8*)(aS + rK + ko);
      b0a = *(const bf16x8*)(bS + ko);
      if constexpr (BCH == 2) b1a = *(const bf16x8*)(bS + rK + ko);
    }
    {
      bf16x8 a[4], b[BJ];
#pragma unroll
      for (int i = 0; i < 4; ++i) a[i] = *(const bf16x8*)&As[wm + i * 16 + c16][vA];
#pragma unroll
      for (int j = 0; j < BJ; ++j) b[j] = *(const bf16x8*)&Bs[wn + j * 16 + c16][vA];
#pragma unroll
      for (int i = 0; i < 4; ++i)
#pragma unroll
        for (int j = 0; j < BJ; ++j)
          acc[i][j] = __builtin_amdgcn_mfma_f32_16x16x32_bf16(a[i], b[j], acc[i][j], 0, 0, 0);
    }
    __syncthreads();
    *(bf16x8*)aD0 = a0b;
    *(bf16x8*)aD1 = a1b;
    *(bf16x8*)bD0 = b0b;
    if constexpr (BCH == 2) *(bf16x8*)bD1 = b1b;
    __syncthreads();
    if (kt + 3 < KI) {
      int ko = (kt + 3) * 32;
      a0b = *(const bf16x8*)(aS + ko);
      a1b = *(const bf16x8*)(aS + rK + ko);
      b0b = *(const bf16x8*)(bS + ko);
      if constexpr (BCH == 2) b1b = *(const bf16x8*)(bS + rK + ko);
    }
    {
      bf16x8 a[4], b[BJ];
#pragma unroll
      for (int i = 0; i < 4; ++i) a[i] = *(const bf16x8*)&As[wm + i * 16 + c16][vA];
#pragma unroll
      for (int j = 0; j < BJ; ++j) b[j] = *(const bf16x8*)&Bs[wn + j * 16 + c16][vA];
#pragma unroll
      for (int i = 0; i < 4; ++i)
#pragma unroll
        for (int j = 0; j < BJ; ++j)
          acc[i][j] = __builtin_amdgcn_mfma_f32_16x16x32_bf16(a[i], b[j], acc[i][j], 0, 0, 0);
    }
  }
  unsigned short* dstb = nullptr;
  int lc0 = 0;
  if (SPLIT3) {
    int which = n0 >> 10;
    dstb = (unsigned short*)(which == 0 ? C0 : which == 1 ? C1 : C2);
    lc0 = n0 & 1023;
  }
#pragma unroll
  for (int j = 0; j < BJ; ++j) {
    int coff = wn + j * 16 + c16;
    float bj = bias[n0 + coff];
#pragma unroll
    for (int i = 0; i < 4; ++i) {
#pragma unroll
      for (int r = 0; r < 4; ++r) {
        int row = m0 + wm + i * 16 + g * 4 + r;
        float cval = acc[i][j][r] + bj;
        if (GELU) cval = gelu_f(cval);
        if (ADDSRC) cval += bf2f(addsrc[(size_t)row * N + n0 + coff]);
        if (SPLIT3) {
          dstb[(size_t)row * 1024 + lc0 + coff] = f2bf(cval);
        } else if (OUT_BF16) {
          ((unsigned short*)C0)[(size_t)row * N + n0 + coff] = f2bf(cval);
        } else {
          ((float*)C0)[(size_t)row * N + n0 + coff] = cval;
        }
      }
    }
  }
}

// ---------------------------------------------------------------------------
// 256x256 8-phase bf16 GEMM v3: snake order + reg fragment reuse (v2) with a
// RE-DERIVED vmcnt schedule. v2's VMW(4)/phase waited for loads only 2 phases
// (~700cyc) old -- under HBM-miss latency (~900cyc) -> stall every phase.
// v3 (FIFO-simulated, load granularity): stage {q0: A0+B0(kt+1), q1: A1,
// q2: B1, q3: none}; waits {q0: VMW(6), q1: VMW(6), q2: none, q3: VMW(4)}.
// Every wait targets loads >=3 phases (~1050cyc) old; every half-tile is
// guaranteed landed (via the previous phases' VMW of ALL waves + barrier)
// one barrier before its first ds_read, including kt=0 after the prologue.
// Slot-overwrite safety: each dbuf slot re-staged a full K-tile (>=7
// barriers) after its last ds_read.
// ---------------------------------------------------------------------------
#define VMW(n) asm volatile("s_waitcnt vmcnt(" #n ")" ::: "memory")
#define BARX() do { asm volatile("" ::: "memory"); \
                    __builtin_amdgcn_s_barrier(); \
                    asm volatile("" ::: "memory"); } while (0)

template <bool GELU, bool SPLIT3>
__global__ __launch_bounds__(512, 2) void gemm256(
    const unsigned short* __restrict__ A, const unsigned short* __restrict__ BT,
    const float* __restrict__ bias, void* C0, void* C1, void* C2,
    int N, int K) {
  __shared__ __align__(16) char lds[2][2][2][16384];
  int tid = threadIdx.x;
  int lane = tid & 63, w = tid >> 6;
  int g = lane >> 4, c16 = lane & 15;
  int wm16 = (w >> 2) << 4;
  int wn16 = (w & 3) << 4;
  // XCD swizzle (nwg % 8 == 0 for both grids)
  int nwg = gridDim.x * gridDim.y;
  int wg = blockIdx.y * gridDim.x + blockIdx.x;
  int cpx = nwg >> 3;
  int sw = (wg & 7) * cpx + (wg >> 3);
  int bx = sw % gridDim.x, by = sw / gridDim.x;
  int m0 = by << 8, n0 = bx << 8;

  int st0 = tid >> 6, ci0 = tid & 63;
  int cp0 = ci0 ^ (((ci0 >> 5) & 1) << 1);
  int sr0 = ((st0 >> 1) << 4) + (cp0 >> 2);
  int sk0 = ((st0 & 1) << 5) + ((cp0 & 3) << 3);
  size_t soff = (size_t)sr0 * K + sk0;

  auto stage = [&](int op, int h, int tt, int d) {
    const unsigned short* base = (op == 0 ? A : BT);
    int row0 = (op == 0 ? m0 : n0) + (h << 7);
    const unsigned short* src = base + (size_t)row0 * K + (tt << 6) + soff;
    unsigned short* dst = (unsigned short*)&lds[op][d][h][tid * 16];
    async16(src, dst);
    async16(src + ((size_t)K << 6), dst + 4096);
  };

  auto foff = [&](int r, int ke) -> int {
    int stt = ((r >> 4) << 1) + (ke >> 5);
    int loc = ((r & 15) << 6) + ((ke & 31) << 1);
    return (stt << 10) + (loc ^ (((r >> 3) & 1) << 5));
  };
  int offA[4][2], offB[2][2];
#pragma unroll
  for (int ii = 0; ii < 4; ++ii)
#pragma unroll
    for (int ks = 0; ks < 2; ++ks)
      offA[ii][ks] = foff(ii * 32 + wm16 + c16, ks * 32 + g * 8);
#pragma unroll
  for (int jj = 0; jj < 2; ++jj)
#pragma unroll
    for (int ks = 0; ks < 2; ++ks)
      offB[jj][ks] = foff(jj * 64 + wn16 + c16, ks * 32 + g * 8);

  f32x4 acc[8][4] = {};

#define MFMA_Q(IH, JH, AF, BF) do {                                           \
    __builtin_amdgcn_s_setprio(1);                                            \
    _Pragma("unroll") for (int ii = 0; ii < 4; ++ii)                          \
      _Pragma("unroll") for (int jj = 0; jj < 2; ++jj) {                      \
        acc[(IH)*4+ii][(JH)*2+jj] = __builtin_amdgcn_mfma_f32_16x16x32_bf16(  \
            AF[ii][0], BF[jj][0], acc[(IH)*4+ii][(JH)*2+jj], 0, 0, 0);        \
        acc[(IH)*4+ii][(JH)*2+jj] = __builtin_amdgcn_mfma_f32_16x16x32_bf16(  \
            AF[ii][1], BF[jj][1], acc[(IH)*4+ii][(JH)*2+jj], 0, 0, 0);        \
      }                                                                       \
    __builtin_amdgcn_s_setprio(0);                                            \
  } while (0)

  // prologue: A0(0),B0(0),A1(0),B1(0) -> dbuf0; wait A0,B0 (keep A1,B1=4)
  stage(0, 0, 0, 0);
  stage(1, 0, 0, 0);
  stage(0, 1, 0, 0);
  stage(1, 1, 0, 0);
  VMW(4);
  BARX();

  const int KT = K >> 6;
  for (int kt = 0; kt < KT; ++kt) {
    int d = kt & 1, dn = d ^ 1;
    int t1 = kt + 1 < KT ? kt + 1 : KT - 1;
    const char* pd = &lds[0][d][0][0];   // A0; A1 +16384; B0 +65536; B1 +81920
    bf16x8 A0f[4][2], A1f[4][2], Bf[2][2];

    // q0: read A0+B0; stage A0(kt+1)+B0(kt+1); VMW(6) waits A1(kt)
#pragma unroll
    for (int ii = 0; ii < 4; ++ii)
#pragma unroll
      for (int ks = 0; ks < 2; ++ks)
        A0f[ii][ks] = *(const bf16x8*)(pd + offA[ii][ks]);
#pragma unroll
    for (int jj = 0; jj < 2; ++jj)
#pragma unroll
      for (int ks = 0; ks < 2; ++ks)
        Bf[jj][ks] = *(const bf16x8*)(pd + 65536 + offB[jj][ks]);
    stage(0, 0, t1, dn);
    stage(1, 0, t1, dn);
    VMW(6);
    BARX();
    MFMA_Q(0, 0, A0f, Bf);
    BARX();

    // q1: read A1 (keep B0); stage A1(kt+1); VMW(6) waits B1(kt)
#pragma unroll
    for (int ii = 0; ii < 4; ++ii)
#pragma unroll
      for (int ks = 0; ks < 2; ++ks)
        A1f[ii][ks] = *(const bf16x8*)(pd + 16384 + offA[ii][ks]);
    stage(0, 1, t1, dn);
    VMW(6);
    BARX();
    MFMA_Q(1, 0, A1f, Bf);
    BARX();

    // q2: read B1 (keep A1); stage B1(kt+1); no wait needed
#pragma unroll
    for (int jj = 0; jj < 2; ++jj)
#pragma unroll
      for (int ks = 0; ks < 2; ++ks)
        Bf[jj][ks] = *(const bf16x8*)(pd + 81920 + offB[jj][ks]);
    stage(1, 1, t1, dn);
    BARX();
    MFMA_Q(1, 1, A1f, Bf);
    BARX();

    // q3: no reads (A0 kept since q0, B1 kept); VMW(4) waits A0/B0(kt+1)
    VMW(4);
    BARX();
    MFMA_Q(0, 1, A0f, Bf);
    BARX();
  }
#undef MFMA_Q
  VMW(0);  // drain dead tail stages

  unsigned short* dstb = nullptr;
  int lc0 = 0;
  if (SPLIT3) {
    int which = n0 >> 10;
    dstb = (unsigned short*)(which == 0 ? C0 : which == 1 ? C1 : C2);
    lc0 = n0 & 1023;
  }
#pragma unroll
  for (int i = 0; i < 8; ++i) {
#pragma unroll
    for (int j = 0; j < 4; ++j) {
      int row_b = m0 + ((i >> 2) << 7) + ((i & 3) << 5) + wm16 + (g << 2);
      int colp = ((j >> 1) << 7) + ((j & 1) << 6) + wn16 + c16;
      float bj = bias[n0 + colp];
#pragma unroll
      for (int r = 0; r < 4; ++r) {
        float cv = acc[i][j][r] + bj;
        if (GELU) cv = gelu_f(cv);
        int row = row_b + r;
        if (SPLIT3) {
          dstb[(size_t)row * 1024 + lc0 + colp] = f2bf(cv);
        } else {
          ((unsigned short*)C0)[(size_t)row * N + n0 + colp] = f2bf(cv);
        }
      }
    }
  }
}

// ---------------------------------------------------------------------------
// MFMA flash attention (round-3 combined version: 128 q-rows, 8 waves,
// mask pre-packed in C-frag layout initializes the QK accumulator).
// ---------------------------------------------------------------------------
__global__ __launch_bounds__(512) void attn_mfma(
    const unsigned short* __restrict__ q, const unsigned short* __restrict__ k,
    const unsigned short* __restrict__ v, const unsigned short* __restrict__ cmP,
    unsigned short* __restrict__ outO) {
  __shared__ __align__(16) unsigned short Ks[2][64][32];
  __shared__ __align__(16) unsigned short Vt[64][72];
  __shared__ __align__(16) unsigned short Ps[128][72];
  int tid = threadIdx.x;
  int wave = tid >> 6, lane = tid & 63;
  int g = lane >> 4, c16 = lane & 15;
  int qt = blockIdx.x, h = blockIdx.y, b = blockIdx.z;
  int s0 = qt * 128;
  int wr = wave * 16;
  size_t headoff = (size_t)b * SS * DD + (size_t)h * SS * 64;
  const unsigned short* qb = q + headoff;
  const unsigned short* kb = k + headoff;
  const unsigned short* vb = v + headoff;
  const unsigned short* csrc =
      cmP + ((((size_t)b * 16 + qt) * 8 + wave) * 32 * 64 + lane) * 16;

  int kkey = tid >> 3, kseg = tid & 7;
  unsigned short* kdst = &Ks[kseg >> 2][kkey][((kseg & 3) ^ swz(kkey)) * 8];
  const unsigned short* ksrc = kb + (size_t)kkey * 64 + kseg * 8;
  const unsigned short* vsrc = vb + (size_t)lane * 64 + wave * 8;
  int vK = (g ^ swz(c16)) * 8;

  bf16x8 qf0, qf1;
  {
    size_t qrow = (size_t)(s0 + wr + c16) * 64;
    qf0 = *(const bf16x8*)(qb + qrow + g * 8);
    qf1 = *(const bf16x8*)(qb + qrow + 32 + g * 8);
  }
  bf16x8 ones;
#pragma unroll
  for (int j = 0; j < 8; ++j) ones[j] = (short)0x3F80;
  f32x4 o[4] = {};
  f32x4 ol = {};
  const float scale2 = 0.18033688f;  // 0.125*log2(e)

  bf16x8 kreg = *(const bf16x8*)(ksrc);
  bf16x8 vreg = *(const bf16x8*)(vsrc);
  bf16x8 cmA = *(const bf16x8*)(csrc);
  bf16x8 cmB = *(const bf16x8*)(csrc + 8);

  for (int kt = 0; kt < 32; ++kt) {
    __syncthreads();
    *(bf16x8*)kdst = kreg;
#pragma unroll
    for (int j = 0; j < 8; ++j) Vt[wave * 8 + j][lane] = (unsigned short)vreg[j];
    __syncthreads();

    int ktn = kt + 1 < 32 ? kt + 1 : 31;
    bf16x8 kregN = *(const bf16x8*)(ksrc + (size_t)ktn * 4096);
    bf16x8 vregN = *(const bf16x8*)(vsrc + (size_t)ktn * 4096);
    bf16x8 cmAN = *(const bf16x8*)(csrc + (size_t)ktn * 1024);
    bf16x8 cmBN = *(const bf16x8*)(csrc + (size_t)ktn * 1024 + 8);

    // QK accumulator initialized with mask*8 (scale2*8 == log2 e)
    f32x4 s[4];
#pragma unroll
    for (int r = 0; r < 4; ++r) {
      s[0][r] = bf2f((unsigned short)cmA[r]);
      s[1][r] = bf2f((unsigned short)cmA[4 + r]);
      s[2][r] = bf2f((unsigned short)cmB[r]);
      s[3][r] = bf2f((unsigned short)cmB[4 + r]);
    }
#pragma unroll
    for (int t = 0; t < 4; ++t) {
      bf16x8 b0 = *(const bf16x8*)&Ks[0][t * 16 + c16][vK];
      bf16x8 b1 = *(const bf16x8*)&Ks[1][t * 16 + c16][vK];
      s[t] = __builtin_amdgcn_mfma_f32_16x16x32_bf16(qf0, b0, s[t], 0, 0, 0);
      s[t] = __builtin_amdgcn_mfma_f32_16x16x32_bf16(qf1, b1, s[t], 0, 0, 0);
    }
#pragma unroll
    for (int t = 0; t < 4; ++t)
#pragma unroll
      for (int r = 0; r < 4; ++r) {
        float p = fast_exp2(s[t][r] * scale2);
        Ps[wr + g * 4 + r][t * 16 + c16] = (unsigned short)(__float_as_uint(p) >> 16);
      }
#pragma unroll
    for (int ks = 0; ks < 2; ++ks) {
      bf16x8 pa = *(const bf16x8*)&Ps[wr + c16][ks * 32 + g * 8];
#pragma unroll
      for (int t2 = 0; t2 < 4; ++t2) {
        bf16x8 vb8 = *(const bf16x8*)&Vt[t2 * 16 + c16][ks * 32 + g * 8];
        o[t2] = __builtin_amdgcn_mfma_f32_16x16x32_bf16(pa, vb8, o[t2], 0, 0, 0);
      }
      ol = __builtin_amdgcn_mfma_f32_16x16x32_bf16(pa, ones, ol, 0, 0, 0);
    }
    kreg = kregN;
    vreg = vregN;
    cmA = cmAN;
    cmB = cmBN;
  }
  float inv[4];
#pragma unroll
  for (int r = 0; r < 4; ++r) inv[r] = fast_rcp(ol[r]);
#pragma unroll
  for (int t2 = 0; t2 < 4; ++t2)
#pragma unroll
    for (int r = 0; r < 4; ++r) {
      int srow = s0 + wr + g * 4 + r;
      outO[headoff + (size_t)srow * 64 + t2 * 16 + c16] = f2bf(o[t2][r] * inv[r]);
    }
}

// ---------------------------------------------------------------------------
extern "C" void kernel_launch(void* const* d_in, const int* in_sizes, int n_in,
                              void* d_out, int out_size, void* d_ws, size_t ws_size,
                              hipStream_t stream) {
  const float* x    = (const float*)d_in[0];
  const float* dis  = (const float*)d_in[1];
  const float* cls  = (const float*)d_in[2];
  const float* wq   = (const float*)d_in[3];
  const float* bq   = (const float*)d_in[4];
  const float* wk   = (const float*)d_in[5];
  const float* bk   = (const float*)d_in[6];
  const float* wv   = (const float*)d_in[7];
  const float* bv   = (const float*)d_in[8];
  const float* ln1g = (const float*)d_in[9];
  const float* ln1b = (const float*)d_in[10];
  const float* ln2g = (const float*)d_in[11];
  const float* ln2b = (const float*)d_in[12];
  const float* w1   = (const float*)d_in[13];
  const float* b1   = (const float*)d_in[14];
  const float* w2   = (const float*)d_in[15];
  const float* b2   = (const float*)d_in[16];
  float* out = (float*)d_out;
  char* ws = (char*)d_ws;

  unsigned short* qkvwT = (unsigned short*)(ws + 0);           // 6 MB
  unsigned short* w1T   = (unsigned short*)(ws + 6291456);     // 8 MB
  unsigned short* w2T   = (unsigned short*)(ws + 14680064);    // 8 MB
  float*          qkvb  = (float*)(ws + 23068672);             // 12 KB
  unsigned short* r1    = (unsigned short*)(ws + 23134208);    // 8 MB: h1 -> attnO
  unsigned short* qbuf  = (unsigned short*)(ws + 31522816);    // 8 MB
  unsigned short* kbuf  = (unsigned short*)(ws + 39911424);    // 8 MB
  unsigned short* vbuf  = (unsigned short*)(ws + 48300032);    // 8 MB
  unsigned short* h2    = (unsigned short*)(ws + 56688640);    // 8 MB
  unsigned short* cmP   = (unsigned short*)(ws + 65077248);    // 16.78 MB
  unsigned short* mm    = (unsigned short*)(ws + 23134208);    // 32 MB overlays r1/q/k/v
  unsigned short* h1 = r1;
  unsigned short* attnO = r1;

  const int rows = BB * SS;  // 4096

  transpose_qkv<<<dim3(DD / 32, DD / 32, 3), 256, 0, stream>>>(wq, wk, wv, qkvwT);
  transpose_to_bf16<<<dim3(MLPD / 32, DD / 32), 256, 0, stream>>>(w1, w1T, DD, MLPD);
  transpose_to_bf16<<<dim3(DD / 32, MLPD / 32), 256, 0, stream>>>(w2, w2T, MLPD, DD);
  concat_bias<<<12, 256, 0, stream>>>(bq, bk, bv, qkvb);
  mask_prep3<<<dim3(16, 8, 8), 256, 0, stream>>>(dis, cls, cmP);

  ln_bf16<false, false><<<rows, 256, 0, stream>>>(x, nullptr, ln1g, ln1b, h1);

  // QKV: 256x256 8-phase v3, SPLIT3 epilogue (192 blocks)
  gemm256<false, true><<<dim3(3072 / 256, rows / 256), 512, 0, stream>>>(
      h1, qkvwT, qkvb, qbuf, kbuf, vbuf, 3072, DD);

  attn_mfma<<<dim3(SS / 128, HH, BB), 512, 0, stream>>>(qbuf, kbuf, vbuf, cmP, attnO);

  ln_bf16<true, true><<<rows, 256, 0, stream>>>(attnO, x, ln2g, ln2b, h2);

  // MLP1: 256x256 8-phase v3 + GELU (256 blocks)
  gemm256<true, false><<<dim3(MLPD / 256, rows / 256), 512, 0, stream>>>(
      h2, w1T, b1, mm, nullptr, nullptr, MLPD, DD);

  // MLP2 (N=1024): legacy 128x64 path + XCD swizzle
  gemm_bf16<64, false, true, false, false><<<dim3(DD / 64, rows / 128), 256, 0, stream>>>(
      mm, w2T, b2, h2, out, nullptr, nullptr, rows, DD, MLPD);
}

// Round 6
// 388.438 us; speedup vs baseline: 1.1023x; 1.0035x over previous
//
#include <hip/hip_runtime.h>
#include <hip/hip_bf16.h>
#include <math.h>

#define BB 2
#define SS 2048
#define DD 1024
#define HH 16
#define MLPD 4096

typedef __attribute__((ext_vector_type(8))) short bf16x8;
typedef __attribute__((ext_vector_type(4))) float f32x4;
typedef __attribute__((ext_vector_type(4))) unsigned short us4;

static __device__ __forceinline__ float fast_exp2(float x) {
#if __has_builtin(__builtin_amdgcn_exp2f)
  return __builtin_amdgcn_exp2f(x);
#else
  return exp2f(x);
#endif
}
static __device__ __forceinline__ float fast_rcp(float x) {
#if __has_builtin(__builtin_amdgcn_rcpf)
  return __builtin_amdgcn_rcpf(x);
#else
  return 1.0f / x;
#endif
}

static __device__ __forceinline__ unsigned short f2bf(float f) {
  union { float f; unsigned int u; } v; v.f = f;
  unsigned int r = v.u + 0x7fffu + ((v.u >> 16) & 1u);
  return (unsigned short)(r >> 16);
}
static __device__ __forceinline__ float bf2f(unsigned short b) {
  return __uint_as_float(((unsigned int)b) << 16);
}

// tanh-form GELU via exp2 (max |err| vs erf-GELU ~3e-4; bf16 noise is 100x)
static __device__ __forceinline__ float gelu_f(float x) {
  float u = x * x;
  float z = x * fmaf(u, 0.0713548162f, 1.59576912f);
  float e = fast_exp2(z * -1.44269504f);
  return x * fast_rcp(1.0f + e);
}

// XOR swizzle for 64B-row LDS tiles
static __device__ __forceinline__ int swz(int row) {
  return (row & 3) ^ ((row >> 2) & 3);
}

// async global->LDS, 16B per lane
static __device__ __forceinline__ void async16(const unsigned short* g, unsigned short* l) {
  __builtin_amdgcn_global_load_lds(
      (const __attribute__((address_space(1))) unsigned int*)g,
      (__attribute__((address_space(3))) unsigned int*)l, 16, 0, 0);
}

// ---------------------------------------------------------------------------
// fp32 [K][N] -> bf16 transposed [N][K], 32x32 LDS tiles
// ---------------------------------------------------------------------------
__global__ __launch_bounds__(256) void transpose_to_bf16(
    const float* __restrict__ src, unsigned short* __restrict__ dst,
    int K, int N) {
  __shared__ float tile[32][33];
  int t = threadIdx.x;
  int c = t & 31, rl = t >> 5;
  int bx = blockIdx.x, by = blockIdx.y;
#pragma unroll
  for (int i = 0; i < 4; ++i) {
    int row = rl * 4 + i;
    tile[row][c] = src[(size_t)(by * 32 + row) * N + bx * 32 + c];
  }
  __syncthreads();
#pragma unroll
  for (int i = 0; i < 4; ++i) {
    int n = rl * 4 + i;
    dst[(size_t)(bx * 32 + n) * K + by * 32 + c] = f2bf(tile[c][n]);
  }
}

// merged QKV weight transpose: grid.z picks wq/wk/wv
__global__ __launch_bounds__(256) void transpose_qkv(
    const float* __restrict__ wq, const float* __restrict__ wk,
    const float* __restrict__ wv, unsigned short* __restrict__ dst) {
  __shared__ float tile[32][33];
  const float* src = blockIdx.z == 0 ? wq : blockIdx.z == 1 ? wk : wv;
  unsigned short* d = dst + (size_t)blockIdx.z * 1024 * 1024;
  int t = threadIdx.x;
  int c = t & 31, rl = t >> 5;
  int bx = blockIdx.x, by = blockIdx.y;
#pragma unroll
  for (int i = 0; i < 4; ++i) {
    int row = rl * 4 + i;
    tile[row][c] = src[(size_t)(by * 32 + row) * DD + bx * 32 + c];
  }
  __syncthreads();
#pragma unroll
  for (int i = 0; i < 4; ++i) {
    int n = rl * 4 + i;
    d[(size_t)(bx * 32 + n) * DD + by * 32 + c] = f2bf(tile[c][n]);
  }
}

__global__ __launch_bounds__(256) void concat_bias(
    const float* __restrict__ bq, const float* __restrict__ bk,
    const float* __restrict__ bv, float* __restrict__ dst) {
  int i = blockIdx.x * 256 + threadIdx.x;
  if (i < 1024) dst[i] = bq[i];
  else if (i < 2048) dst[i] = bk[i - 1024];
  else if (i < 3072) dst[i] = bv[i - 2048];
}

// ---------------------------------------------------------------------------
// Mask pre-pack v3 (LDS-staged, float4 loads). Layout:
//   cmP[b][qt(16)][wave(8)][kt(32)][lane(64)][16]
//   chunk[t*4+r] = (dis+cls)[qt*128+wave*16+(lane>>4)*4+r][kt*64+t*16+(lane&15)] * 8
// ---------------------------------------------------------------------------
__global__ __launch_bounds__(256) void mask_prep3(
    const float* __restrict__ dis, const float* __restrict__ cls,
    unsigned short* __restrict__ cmP) {
  __shared__ unsigned short sm[16][512];
  int qtO = blockIdx.x, waveO = blockIdx.y;
  int b = blockIdx.z >> 2, ktg = blockIdx.z & 3;
  int t = threadIdx.x;
  int row0 = qtO * 128 + waveO * 16;
  int col0 = ktg * 512;
  const float* db = dis + (size_t)b * SS * SS;
  const float* cb = cls + (size_t)b * SS * SS;
  int lrow = t >> 4, lcg = t & 15;
#pragma unroll
  for (int shot = 0; shot < 8; ++shot) {
    int cc = lcg * 4 + shot * 64;
    size_t idx = (size_t)(row0 + lrow) * SS + col0 + cc;
    float4 d4 = *(const float4*)(db + idx);
    float4 c4 = *(const float4*)(cb + idx);
    us4 o;
    o[0] = f2bf((d4.x + c4.x) * 8.0f);
    o[1] = f2bf((d4.y + c4.y) * 8.0f);
    o[2] = f2bf((d4.z + c4.z) * 8.0f);
    o[3] = f2bf((d4.w + c4.w) * 8.0f);
    *(us4*)&sm[lrow][cc] = o;
  }
  __syncthreads();
  int ktL = t >> 5, lp = t & 31;
  unsigned short* ob =
      cmP + ((((size_t)b * 16 + qtO) * 8 + waveO) * 32 + ktg * 8 + ktL) * 64 * 16;
#pragma unroll
  for (int li = 0; li < 2; ++li) {
    int l = lp * 2 + li;
    int g = l >> 4, c16 = l & 15;
    short v[16];
#pragma unroll
    for (int t4 = 0; t4 < 4; ++t4)
#pragma unroll
      for (int r = 0; r < 4; ++r)
        v[t4 * 4 + r] = (short)sm[g * 4 + r][ktL * 64 + t4 * 16 + c16];
    unsigned short* o = ob + (size_t)l * 16;
    *(bf16x8*)(o) = *(bf16x8*)&v[0];
    *(bf16x8*)(o + 8) = *(bf16x8*)&v[8];
  }
}

// ---------------------------------------------------------------------------
// LayerNorm -> bf16 out
// ---------------------------------------------------------------------------
template <bool BF_IN, bool ADD>
__global__ __launch_bounds__(256) void ln_bf16(
    const void* __restrict__ in, const float* __restrict__ add,
    const float* __restrict__ g, const float* __restrict__ beta,
    unsigned short* __restrict__ out) {
  int row = blockIdx.x;
  int t = threadIdx.x;
  float x[4];
  if (BF_IN) {
    us4 b4 = *(const us4*)((const unsigned short*)in + (size_t)row * DD + t * 4);
#pragma unroll
    for (int i = 0; i < 4; ++i) x[i] = bf2f(b4[i]);
  } else {
    float4 f4 = *(const float4*)((const float*)in + (size_t)row * DD + t * 4);
    x[0] = f4.x; x[1] = f4.y; x[2] = f4.z; x[3] = f4.w;
  }
  if (ADD) {
    float4 a4 = *(const float4*)(add + (size_t)row * DD + t * 4);
    x[0] += a4.x; x[1] += a4.y; x[2] += a4.z; x[3] += a4.w;
  }
  float s1 = x[0] + x[1] + x[2] + x[3];
  float s2 = x[0] * x[0] + x[1] * x[1] + x[2] * x[2] + x[3] * x[3];
#pragma unroll
  for (int off = 32; off > 0; off >>= 1) {
    s1 += __shfl_down(s1, off);
    s2 += __shfl_down(s2, off);
  }
  __shared__ float sa[4], sb[4];
  int wid = t >> 6;
  if ((t & 63) == 0) { sa[wid] = s1; sb[wid] = s2; }
  __syncthreads();
  s1 = sa[0] + sa[1] + sa[2] + sa[3];
  s2 = sb[0] + sb[1] + sb[2] + sb[3];
  float mean = s1 * (1.0f / 1024.0f);
  float var = s2 * (1.0f / 1024.0f) - mean * mean;
  float rstd = rsqrtf(var + 1e-5f);
  float4 gv = *(const float4*)(g + t * 4);
  float4 bv = *(const float4*)(beta + t * 4);
  us4 o;
  o[0] = f2bf((x[0] - mean) * rstd * gv.x + bv.x);
  o[1] = f2bf((x[1] - mean) * rstd * gv.y + bv.y);
  o[2] = f2bf((x[2] - mean) * rstd * gv.z + bv.z);
  o[3] = f2bf((x[3] - mean) * rstd * gv.w + bv.w);
  *(us4*)(out + (size_t)row * DD + t * 4) = o;
}

// ---------------------------------------------------------------------------
// Legacy bf16 MFMA GEMM (128xBN tile, reg-prefetch) for MLP2 (N=1024),
// with XCD-contiguous block swizzle (r4->r5: FETCH amplification fix, WIN).
// ---------------------------------------------------------------------------
template <int BN, bool GELU, bool ADDSRC, bool OUT_BF16, bool SPLIT3>
__global__ __launch_bounds__(256) void gemm_bf16(
    const unsigned short* __restrict__ A, const unsigned short* __restrict__ BT,
    const float* __restrict__ bias, const unsigned short* __restrict__ addsrc,
    void* C0, void* C1, void* C2, int M, int N, int K) {
  constexpr int BJ = BN / 32;
  constexpr int BCH = BN / 64;
  __shared__ __align__(16) unsigned short As[128][32];
  __shared__ __align__(16) unsigned short Bs[BN][32];
  int tid = threadIdx.x;
  int wave = tid >> 6, lane = tid & 63;
  int g = lane >> 4, c16 = lane & 15;
  int nwg = gridDim.x * gridDim.y;
  int wg = blockIdx.y * gridDim.x + blockIdx.x;
  int cpx = nwg >> 3;
  int sw = (wg & 7) * cpx + (wg >> 3);
  int bxs = sw % gridDim.x, bys = sw / gridDim.x;
  int m0 = bys * 128, n0 = bxs * BN;
  int wm = (wave >> 1) * 64, wn = (wave & 1) * (BN / 2);
  int lrow = lane >> 2, lq = lane & 3;
  int dq = (lq ^ swz(lrow)) * 8;
  const unsigned short* aS = A + (size_t)(m0 + wave * 32 + lrow) * K + lq * 8;
  unsigned short* aD0 = &As[wave * 32 + lrow][dq];
  unsigned short* aD1 = &As[wave * 32 + 16 + lrow][dq];
  const unsigned short* bS = BT + (size_t)(n0 + wave * (BCH * 16) + lrow) * K + lq * 8;
  unsigned short* bD0 = &Bs[wave * (BCH * 16) + lrow][dq];
  unsigned short* bD1 = &Bs[(wave * (BCH * 16) + 16 + lrow) % BN][dq];
  int vA = (g ^ swz(c16)) * 8;
  const int KI = K / 32;
  const size_t rK = 16 * (size_t)K;

  bf16x8 a0a = *(const bf16x8*)(aS);
  bf16x8 a1a = *(const bf16x8*)(aS + rK);
  bf16x8 b0a = *(const bf16x8*)(bS);
  bf16x8 b1a;
  if constexpr (BCH == 2) b1a = *(const bf16x8*)(bS + rK);
  bf16x8 a0b = *(const bf16x8*)(aS + 32);
  bf16x8 a1b = *(const bf16x8*)(aS + rK + 32);
  bf16x8 b0b = *(const bf16x8*)(bS + 32);
  bf16x8 b1b;
  if constexpr (BCH == 2) b1b = *(const bf16x8*)(bS + rK + 32);

  f32x4 acc[4][BJ] = {};
  for (int kt = 0; kt < KI; kt += 2) {
    __syncthreads();
    *(bf16x8*)aD0 = a0a;
    *(bf16x8*)aD1 = a1a;
    *(bf16x8*)bD0 = b0a;
    if constexpr (BCH == 2) *(bf16x8*)bD1 = b1a;
    __syncthreads();
    if (kt + 2 < KI) {
      int ko = (kt + 2) * 32;
      a0a = *(const bf16x8*)(aS + ko);
      a1a = *(const bf16x8*)(aS + rK + ko);
      b0a = *(const bf16x8*)(bS + ko);
      if constexpr (BCH == 2) b1a = *(const bf16x8*)(bS + rK + ko);
    }
    {
      bf16x8 a[4], b[BJ];
#pragma unroll
      for (int i = 0; i < 4; ++i) a[i] = *(const bf16x8*)&As[wm + i * 16 + c16][vA];
#pragma unroll
      for (int j = 0; j < BJ; ++j) b[j] = *(const bf16x8*)&Bs[wn + j * 16 + c16][vA];
#pragma unroll
      for (int i = 0; i < 4; ++i)
#pragma unroll
        for (int j = 0; j < BJ; ++j)
          acc[i][j] = __builtin_amdgcn_mfma_f32_16x16x32_bf16(a[i], b[j], acc[i][j], 0, 0, 0);
    }
    __syncthreads();
    *(bf16x8*)aD0 = a0b;
    *(bf16x8*)aD1 = a1b;
    *(bf16x8*)bD0 = b0b;
    if constexpr (BCH == 2) *(bf16x8*)bD1 = b1b;
    __syncthreads();
    if (kt + 3 < KI) {
      int ko = (kt + 3) * 32;
      a0b = *(const bf16x8*)(aS + ko);
      a1b = *(const bf16x8*)(aS + rK + ko);
      b0b = *(const bf16x8*)(bS + ko);
      if constexpr (BCH == 2) b1b = *(const bf16x8*)(bS + rK + ko);
    }
    {
      bf16x8 a[4], b[BJ];
#pragma unroll
      for (int i = 0; i < 4; ++i) a[i] = *(const bf16x8*)&As[wm + i * 16 + c16][vA];
#pragma unroll
      for (int j = 0; j < BJ; ++j) b[j] = *(const bf16x8*)&Bs[wn + j * 16 + c16][vA];
#pragma unroll
      for (int i = 0; i < 4; ++i)
#pragma unroll
        for (int j = 0; j < BJ; ++j)
          acc[i][j] = __builtin_amdgcn_mfma_f32_16x16x32_bf16(a[i], b[j], acc[i][j], 0, 0, 0);
    }
  }
  unsigned short* dstb = nullptr;
  int lc0 = 0;
  if (SPLIT3) {
    int which = n0 >> 10;
    dstb = (unsigned short*)(which == 0 ? C0 : which == 1 ? C1 : C2);
    lc0 = n0 & 1023;
  }
#pragma unroll
  for (int j = 0; j < BJ; ++j) {
    int coff = wn + j * 16 + c16;
    float bj = bias[n0 + coff];
#pragma unroll
    for (int i = 0; i < 4; ++i) {
#pragma unroll
      for (int r = 0; r < 4; ++r) {
        int row = m0 + wm + i * 16 + g * 4 + r;
        float cval = acc[i][j][r] + bj;
        if (GELU) cval = gelu_f(cval);
        if (ADDSRC) cval += bf2f(addsrc[(size_t)row * N + n0 + coff]);
        if (SPLIT3) {
          dstb[(size_t)row * 1024 + lc0 + coff] = f2bf(cval);
        } else if (OUT_BF16) {
          ((unsigned short*)C0)[(size_t)row * N + n0 + coff] = f2bf(cval);
        } else {
          ((float*)C0)[(size_t)row * N + n0 + coff] = cval;
        }
      }
    }
  }
}

// ---------------------------------------------------------------------------
// 256x256 8-phase bf16 GEMM v3 (snake + reg reuse + derived vmcnt). r5 best.
// ---------------------------------------------------------------------------
#define VMW(n) asm volatile("s_waitcnt vmcnt(" #n ")" ::: "memory")
#define BARX() do { asm volatile("" ::: "memory"); \
                    __builtin_amdgcn_s_barrier(); \
                    asm volatile("" ::: "memory"); } while (0)

template <bool GELU, bool SPLIT3>
__global__ __launch_bounds__(512, 2) void gemm256(
    const unsigned short* __restrict__ A, const unsigned short* __restrict__ BT,
    const float* __restrict__ bias, void* C0, void* C1, void* C2,
    int N, int K) {
  __shared__ __align__(16) char lds[2][2][2][16384];
  int tid = threadIdx.x;
  int lane = tid & 63, w = tid >> 6;
  int g = lane >> 4, c16 = lane & 15;
  int wm16 = (w >> 2) << 4;
  int wn16 = (w & 3) << 4;
  int nwg = gridDim.x * gridDim.y;
  int wg = blockIdx.y * gridDim.x + blockIdx.x;
  int cpx = nwg >> 3;
  int sw = (wg & 7) * cpx + (wg >> 3);
  int bx = sw % gridDim.x, by = sw / gridDim.x;
  int m0 = by << 8, n0 = bx << 8;

  int st0 = tid >> 6, ci0 = tid & 63;
  int cp0 = ci0 ^ (((ci0 >> 5) & 1) << 1);
  int sr0 = ((st0 >> 1) << 4) + (cp0 >> 2);
  int sk0 = ((st0 & 1) << 5) + ((cp0 & 3) << 3);
  size_t soff = (size_t)sr0 * K + sk0;

  auto stage = [&](int op, int h, int tt, int d) {
    const unsigned short* base = (op == 0 ? A : BT);
    int row0 = (op == 0 ? m0 : n0) + (h << 7);
    const unsigned short* src = base + (size_t)row0 * K + (tt << 6) + soff;
    unsigned short* dst = (unsigned short*)&lds[op][d][h][tid * 16];
    async16(src, dst);
    async16(src + ((size_t)K << 6), dst + 4096);
  };

  auto foff = [&](int r, int ke) -> int {
    int stt = ((r >> 4) << 1) + (ke >> 5);
    int loc = ((r & 15) << 6) + ((ke & 31) << 1);
    return (stt << 10) + (loc ^ (((r >> 3) & 1) << 5));
  };
  int offA[4][2], offB[2][2];
#pragma unroll
  for (int ii = 0; ii < 4; ++ii)
#pragma unroll
    for (int ks = 0; ks < 2; ++ks)
      offA[ii][ks] = foff(ii * 32 + wm16 + c16, ks * 32 + g * 8);
#pragma unroll
  for (int jj = 0; jj < 2; ++jj)
#pragma unroll
    for (int ks = 0; ks < 2; ++ks)
      offB[jj][ks] = foff(jj * 64 + wn16 + c16, ks * 32 + g * 8);

  f32x4 acc[8][4] = {};

#define MFMA_Q(IH, JH, AF, BF) do {                                           \
    __builtin_amdgcn_s_setprio(1);                                            \
    _Pragma("unroll") for (int ii = 0; ii < 4; ++ii)                          \
      _Pragma("unroll") for (int jj = 0; jj < 2; ++jj) {                      \
        acc[(IH)*4+ii][(JH)*2+jj] = __builtin_amdgcn_mfma_f32_16x16x32_bf16(  \
            AF[ii][0], BF[jj][0], acc[(IH)*4+ii][(JH)*2+jj], 0, 0, 0);        \
        acc[(IH)*4+ii][(JH)*2+jj] = __builtin_amdgcn_mfma_f32_16x16x32_bf16(  \
            AF[ii][1], BF[jj][1], acc[(IH)*4+ii][(JH)*2+jj], 0, 0, 0);        \
      }                                                                       \
    __builtin_amdgcn_s_setprio(0);                                            \
  } while (0)

  stage(0, 0, 0, 0);
  stage(1, 0, 0, 0);
  stage(0, 1, 0, 0);
  stage(1, 1, 0, 0);
  VMW(4);
  BARX();

  const int KT = K >> 6;
  for (int kt = 0; kt < KT; ++kt) {
    int d = kt & 1, dn = d ^ 1;
    int t1 = kt + 1 < KT ? kt + 1 : KT - 1;
    const char* pd = &lds[0][d][0][0];
    bf16x8 A0f[4][2], A1f[4][2], Bf[2][2];

#pragma unroll
    for (int ii = 0; ii < 4; ++ii)
#pragma unroll
      for (int ks = 0; ks < 2; ++ks)
        A0f[ii][ks] = *(const bf16x8*)(pd + offA[ii][ks]);
#pragma unroll
    for (int jj = 0; jj < 2; ++jj)
#pragma unroll
      for (int ks = 0; ks < 2; ++ks)
        Bf[jj][ks] = *(const bf16x8*)(pd + 65536 + offB[jj][ks]);
    stage(0, 0, t1, dn);
    stage(1, 0, t1, dn);
    VMW(6);
    BARX();
    MFMA_Q(0, 0, A0f, Bf);
    BARX();

#pragma unroll
    for (int ii = 0; ii < 4; ++ii)
#pragma unroll
      for (int ks = 0; ks < 2; ++ks)
        A1f[ii][ks] = *(const bf16x8*)(pd + 16384 + offA[ii][ks]);
    stage(0, 1, t1, dn);
    VMW(6);
    BARX();
    MFMA_Q(1, 0, A1f, Bf);
    BARX();

#pragma unroll
    for (int jj = 0; jj < 2; ++jj)
#pragma unroll
      for (int ks = 0; ks < 2; ++ks)
        Bf[jj][ks] = *(const bf16x8*)(pd + 81920 + offB[jj][ks]);
    stage(1, 1, t1, dn);
    BARX();
    MFMA_Q(1, 1, A1f, Bf);
    BARX();

    VMW(4);
    BARX();
    MFMA_Q(0, 1, A0f, Bf);
    BARX();
  }
#undef MFMA_Q
  VMW(0);

  unsigned short* dstb = nullptr;
  int lc0 = 0;
  if (SPLIT3) {
    int which = n0 >> 10;
    dstb = (unsigned short*)(which == 0 ? C0 : which == 1 ? C1 : C2);
    lc0 = n0 & 1023;
  }
#pragma unroll
  for (int i = 0; i < 8; ++i) {
#pragma unroll
    for (int j = 0; j < 4; ++j) {
      int row_b = m0 + ((i >> 2) << 7) + ((i & 3) << 5) + wm16 + (g << 2);
      int colp = ((j >> 1) << 7) + ((j & 1) << 6) + wn16 + c16;
      float bj = bias[n0 + colp];
#pragma unroll
      for (int r = 0; r < 4; ++r) {
        float cv = acc[i][j][r] + bj;
        if (GELU) cv = gelu_f(cv);
        int row = row_b + r;
        if (SPLIT3) {
          dstb[(size_t)row * 1024 + lc0 + colp] = f2bf(cv);
        } else {
          ((unsigned short*)C0)[(size_t)row * N + n0 + colp] = f2bf(cv);
        }
      }
    }
  }
}

// ---------------------------------------------------------------------------
// MFMA flash attention v5: 256 q-rows/block, 8 waves, 32 q-rows/wave
// (two 16-row sub-tiles). Shared Ks/Vt fragment reads serve 2x MFMA work
// -> per-CU LDS-pipe cycles/kt drop 0.65x (attn is LDS-issue-bound: r5
// model 348cyc/wave/kt matched 79us measured). Ps writes use a column-block
// rotation (col' = ((t + ((prow>>2)&3))&3)*16 + c16) -> conflict-free
// (old layout: 4-way, the 10.49M SQ_LDS_BANK_CONFLICT). Grid=256=1/CU with
// head-affine XCD remap (all 8 q-blocks of a head share one L2).
// ---------------------------------------------------------------------------
__global__ __launch_bounds__(512) void attn_mfma256(
    const unsigned short* __restrict__ q, const unsigned short* __restrict__ k,
    const unsigned short* __restrict__ v, const unsigned short* __restrict__ cmP,
    unsigned short* __restrict__ outO) {
  __shared__ __align__(16) unsigned short Ks[2][64][32];
  __shared__ __align__(16) unsigned short Vt[64][72];
  __shared__ __align__(16) unsigned short Ps[256][72];
  int tid = threadIdx.x;
  int wave = tid >> 6, lane = tid & 63;
  int g = lane >> 4, c16 = lane & 15;
  // head-affine XCD remap: hw id w -> (qt,h,b) with w%8 constant per head
  int w = blockIdx.x + 8 * blockIdx.y + 128 * blockIdx.z;
  int qt = (w >> 4) & 7;
  int b = (w >> 3) & 1;
  int h = (w & 7) | (((w >> 7) & 1) << 3);
  int s0 = qt * 256;
  int wr = wave * 32;
  size_t headoff = (size_t)b * SS * DD + (size_t)h * SS * 64;
  const unsigned short* qb = q + headoff;
  const unsigned short* kb = k + headoff;
  const unsigned short* vb = v + headoff;
  // mask streams for the two 16-row sub-tiles (cmP indexed by old 128-row
  // tiling: qt128 = R>>7, waveO = (R>>4)&7 for R = global row base)
  int qtA = qt * 2 + (wave >> 2);
  int wOA = (wave & 3) * 2;
  const unsigned short* csrcA =
      cmP + ((((size_t)b * 16 + qtA) * 8 + wOA) * 2048 + lane) * 16;
  const unsigned short* csrcB = csrcA + 2048 * 16;

  int kkey = tid >> 3, kseg = tid & 7;
  unsigned short* kdst = &Ks[kseg >> 2][kkey][((kseg & 3) ^ swz(kkey)) * 8];
  const unsigned short* ksrc = kb + (size_t)kkey * 64 + kseg * 8;
  const unsigned short* vsrc = vb + (size_t)lane * 64 + wave * 8;
  int vK = (g ^ swz(c16)) * 8;

  bf16x8 qf0A, qf1A, qf0B, qf1B;
  {
    size_t qrowA = (size_t)(s0 + wr + c16) * 64;
    size_t qrowB = (size_t)(s0 + wr + 16 + c16) * 64;
    qf0A = *(const bf16x8*)(qb + qrowA + g * 8);
    qf1A = *(const bf16x8*)(qb + qrowA + 32 + g * 8);
    qf0B = *(const bf16x8*)(qb + qrowB + g * 8);
    qf1B = *(const bf16x8*)(qb + qrowB + 32 + g * 8);
  }
  bf16x8 ones;
#pragma unroll
  for (int j = 0; j < 8; ++j) ones[j] = (short)0x3F80;
  f32x4 oA[4] = {}, oB[4] = {};
  f32x4 olA = {}, olB = {};
  const float scale2 = 0.18033688f;  // 0.125*log2(e)

  bf16x8 kreg = *(const bf16x8*)(ksrc);
  bf16x8 vreg = *(const bf16x8*)(vsrc);
  bf16x8 cmA0 = *(const bf16x8*)(csrcA);
  bf16x8 cmA1 = *(const bf16x8*)(csrcA + 8);
  bf16x8 cmB0 = *(const bf16x8*)(csrcB);
  bf16x8 cmB1 = *(const bf16x8*)(csrcB + 8);

  for (int kt = 0; kt < 32; ++kt) {
    __syncthreads();
    *(bf16x8*)kdst = kreg;
#pragma unroll
    for (int j = 0; j < 8; ++j) Vt[wave * 8 + j][lane] = (unsigned short)vreg[j];
    __syncthreads();

    int ktn = kt + 1 < 32 ? kt + 1 : 31;
    bf16x8 kregN = *(const bf16x8*)(ksrc + (size_t)ktn * 4096);
    bf16x8 vregN = *(const bf16x8*)(vsrc + (size_t)ktn * 4096);
    bf16x8 cmA0N = *(const bf16x8*)(csrcA + (size_t)ktn * 1024);
    bf16x8 cmA1N = *(const bf16x8*)(csrcA + (size_t)ktn * 1024 + 8);
    bf16x8 cmB0N = *(const bf16x8*)(csrcB + (size_t)ktn * 1024);
    bf16x8 cmB1N = *(const bf16x8*)(csrcB + (size_t)ktn * 1024 + 8);

    // QK for both sub-tiles, sharing the Ks fragment reads
    f32x4 sA[4], sB[4];
#pragma unroll
    for (int r = 0; r < 4; ++r) {
      sA[0][r] = bf2f((unsigned short)cmA0[r]);
      sA[1][r] = bf2f((unsigned short)cmA0[4 + r]);
      sA[2][r] = bf2f((unsigned short)cmA1[r]);
      sA[3][r] = bf2f((unsigned short)cmA1[4 + r]);
      sB[0][r] = bf2f((unsigned short)cmB0[r]);
      sB[1][r] = bf2f((unsigned short)cmB0[4 + r]);
      sB[2][r] = bf2f((unsigned short)cmB1[r]);
      sB[3][r] = bf2f((unsigned short)cmB1[4 + r]);
    }
#pragma unroll
    for (int t = 0; t < 4; ++t) {
      bf16x8 b0 = *(const bf16x8*)&Ks[0][t * 16 + c16][vK];
      bf16x8 b1 = *(const bf16x8*)&Ks[1][t * 16 + c16][vK];
      sA[t] = __builtin_amdgcn_mfma_f32_16x16x32_bf16(qf0A, b0, sA[t], 0, 0, 0);
      sA[t] = __builtin_amdgcn_mfma_f32_16x16x32_bf16(qf1A, b1, sA[t], 0, 0, 0);
      sB[t] = __builtin_amdgcn_mfma_f32_16x16x32_bf16(qf0B, b0, sB[t], 0, 0, 0);
      sB[t] = __builtin_amdgcn_mfma_f32_16x16x32_bf16(qf1B, b1, sB[t], 0, 0, 0);
    }
    // exp -> Ps with rotation (conflict-free; rot = (prow>>2)&3 = g here)
#pragma unroll
    for (int t = 0; t < 4; ++t) {
      int colw = ((t + g) & 3) * 16 + c16;
#pragma unroll
      for (int r = 0; r < 4; ++r) {
        float pA = fast_exp2(sA[t][r] * scale2);
        Ps[wr + g * 4 + r][colw] = (unsigned short)(__float_as_uint(pA) >> 16);
        float pB = fast_exp2(sB[t][r] * scale2);
        Ps[wr + 16 + g * 4 + r][colw] = (unsigned short)(__float_as_uint(pB) >> 16);
      }
    }
    // PV: Vt fragment reads shared across both sub-tiles
#pragma unroll
    for (int ks = 0; ks < 2; ++ks) {
      int ttc = ((ks * 2 + (g >> 1)) + ((c16 >> 2) & 3)) & 3;  // rot = (prow2>>2)&3
      int colp = ttc * 16 + (g & 1) * 8;
      bf16x8 paA = *(const bf16x8*)&Ps[wr + c16][colp];
      bf16x8 paB = *(const bf16x8*)&Ps[wr + 16 + c16][colp];
#pragma unroll
      for (int t2 = 0; t2 < 4; ++t2) {
        bf16x8 vb8 = *(const bf16x8*)&Vt[t2 * 16 + c16][ks * 32 + g * 8];
        oA[t2] = __builtin_amdgcn_mfma_f32_16x16x32_bf16(paA, vb8, oA[t2], 0, 0, 0);
        oB[t2] = __builtin_amdgcn_mfma_f32_16x16x32_bf16(paB, vb8, oB[t2], 0, 0, 0);
      }
      olA = __builtin_amdgcn_mfma_f32_16x16x32_bf16(paA, ones, olA, 0, 0, 0);
      olB = __builtin_amdgcn_mfma_f32_16x16x32_bf16(paB, ones, olB, 0, 0, 0);
    }
    kreg = kregN;
    vreg = vregN;
    cmA0 = cmA0N; cmA1 = cmA1N;
    cmB0 = cmB0N; cmB1 = cmB1N;
  }
  float invA[4], invB[4];
#pragma unroll
  for (int r = 0; r < 4; ++r) {
    invA[r] = fast_rcp(olA[r]);
    invB[r] = fast_rcp(olB[r]);
  }
#pragma unroll
  for (int t2 = 0; t2 < 4; ++t2)
#pragma unroll
    for (int r = 0; r < 4; ++r) {
      int srowA = s0 + wr + g * 4 + r;
      int srowB = srowA + 16;
      outO[headoff + (size_t)srowA * 64 + t2 * 16 + c16] = f2bf(oA[t2][r] * invA[r]);
      outO[headoff + (size_t)srowB * 64 + t2 * 16 + c16] = f2bf(oB[t2][r] * invB[r]);
    }
}

// ---------------------------------------------------------------------------
extern "C" void kernel_launch(void* const* d_in, const int* in_sizes, int n_in,
                              void* d_out, int out_size, void* d_ws, size_t ws_size,
                              hipStream_t stream) {
  const float* x    = (const float*)d_in[0];
  const float* dis  = (const float*)d_in[1];
  const float* cls  = (const float*)d_in[2];
  const float* wq   = (const float*)d_in[3];
  const float* bq   = (const float*)d_in[4];
  const float* wk   = (const float*)d_in[5];
  const float* bk   = (const float*)d_in[6];
  const float* wv   = (const float*)d_in[7];
  const float* bv   = (const float*)d_in[8];
  const float* ln1g = (const float*)d_in[9];
  const float* ln1b = (const float*)d_in[10];
  const float* ln2g = (const float*)d_in[11];
  const float* ln2b = (const float*)d_in[12];
  const float* w1   = (const float*)d_in[13];
  const float* b1   = (const float*)d_in[14];
  const float* w2   = (const float*)d_in[15];
  const float* b2   = (const float*)d_in[16];
  float* out = (float*)d_out;
  char* ws = (char*)d_ws;

  unsigned short* qkvwT = (unsigned short*)(ws + 0);           // 6 MB
  unsigned short* w1T   = (unsigned short*)(ws + 6291456);     // 8 MB
  unsigned short* w2T   = (unsigned short*)(ws + 14680064);    // 8 MB
  float*          qkvb  = (float*)(ws + 23068672);             // 12 KB
  unsigned short* r1    = (unsigned short*)(ws + 23134208);    // 8 MB: h1 -> attnO
  unsigned short* qbuf  = (unsigned short*)(ws + 31522816);    // 8 MB
  unsigned short* kbuf  = (unsigned short*)(ws + 39911424);    // 8 MB
  unsigned short* vbuf  = (unsigned short*)(ws + 48300032);    // 8 MB
  unsigned short* h2    = (unsigned short*)(ws + 56688640);    // 8 MB
  unsigned short* cmP   = (unsigned short*)(ws + 65077248);    // 16.78 MB
  unsigned short* mm    = (unsigned short*)(ws + 23134208);    // 32 MB overlays r1/q/k/v
  unsigned short* h1 = r1;
  unsigned short* attnO = r1;

  const int rows = BB * SS;  // 4096

  transpose_qkv<<<dim3(DD / 32, DD / 32, 3), 256, 0, stream>>>(wq, wk, wv, qkvwT);
  transpose_to_bf16<<<dim3(MLPD / 32, DD / 32), 256, 0, stream>>>(w1, w1T, DD, MLPD);
  transpose_to_bf16<<<dim3(DD / 32, MLPD / 32), 256, 0, stream>>>(w2, w2T, MLPD, DD);
  concat_bias<<<12, 256, 0, stream>>>(bq, bk, bv, qkvb);
  mask_prep3<<<dim3(16, 8, 8), 256, 0, stream>>>(dis, cls, cmP);

  ln_bf16<false, false><<<rows, 256, 0, stream>>>(x, nullptr, ln1g, ln1b, h1);

  // QKV: 256x256 8-phase v3, SPLIT3 epilogue (192 blocks)
  gemm256<false, true><<<dim3(3072 / 256, rows / 256), 512, 0, stream>>>(
      h1, qkvwT, qkvb, qbuf, kbuf, vbuf, 3072, DD);

  // attn v5: 256-row blocks, grid 256 = 1/CU
  attn_mfma256<<<dim3(SS / 256, HH, BB), 512, 0, stream>>>(
      qbuf, kbuf, vbuf, cmP, attnO);

  ln_bf16<true, true><<<rows, 256, 0, stream>>>(attnO, x, ln2g, ln2b, h2);

  // MLP1: 256x256 8-phase v3 + GELU (256 blocks)
  gemm256<true, false><<<dim3(MLPD / 256, rows / 256), 512, 0, stream>>>(
      h2, w1T, b1, mm, nullptr, nullptr, MLPD, DD);

  // MLP2 (N=1024): legacy 128x64 path + XCD swizzle
  gemm_bf16<64, false, true, false, false><<<dim3(DD / 64, rows / 128), 256, 0, stream>>>(
      mm, w2T, b2, h2, out, nullptr, nullptr, rows, DD, MLPD);
}

// Round 7
// 380.295 us; speedup vs baseline: 1.1259x; 1.0214x over previous
//
#include <hip/hip_runtime.h>
#include <hip/hip_bf16.h>
#include <math.h>

#define BB 2
#define SS 2048
#define DD 1024
#define HH 16
#define MLPD 4096

typedef __attribute__((ext_vector_type(8))) short bf16x8;
typedef __attribute__((ext_vector_type(4))) float f32x4;
typedef __attribute__((ext_vector_type(4))) unsigned short us4;

static __device__ __forceinline__ float fast_exp2(float x) {
#if __has_builtin(__builtin_amdgcn_exp2f)
  return __builtin_amdgcn_exp2f(x);
#else
  return exp2f(x);
#endif
}
static __device__ __forceinline__ float fast_rcp(float x) {
#if __has_builtin(__builtin_amdgcn_rcpf)
  return __builtin_amdgcn_rcpf(x);
#else
  return 1.0f / x;
#endif
}

static __device__ __forceinline__ unsigned short f2bf(float f) {
  union { float f; unsigned int u; } v; v.f = f;
  unsigned int r = v.u + 0x7fffu + ((v.u >> 16) & 1u);
  return (unsigned short)(r >> 16);
}
static __device__ __forceinline__ float bf2f(unsigned short b) {
  return __uint_as_float(((unsigned int)b) << 16);
}
// truncating bf16 pack of two floats (lo -> low half). Same truncation the
// proven attn used for P (positive values, absmax-safe).
static __device__ __forceinline__ unsigned int packbf(float lo, float hi) {
  return (__float_as_uint(lo) >> 16) | (__float_as_uint(hi) & 0xFFFF0000u);
}

// tanh-form GELU via exp2 (max |err| vs erf-GELU ~3e-4; bf16 noise is 100x)
static __device__ __forceinline__ float gelu_f(float x) {
  float u = x * x;
  float z = x * fmaf(u, 0.0713548162f, 1.59576912f);
  float e = fast_exp2(z * -1.44269504f);
  return x * fast_rcp(1.0f + e);
}

// XOR swizzle for 64B-row LDS tiles
static __device__ __forceinline__ int swz(int row) {
  return (row & 3) ^ ((row >> 2) & 3);
}

// async global->LDS, 16B per lane
static __device__ __forceinline__ void async16(const unsigned short* g, unsigned short* l) {
  __builtin_amdgcn_global_load_lds(
      (const __attribute__((address_space(1))) unsigned int*)g,
      (__attribute__((address_space(3))) unsigned int*)l, 16, 0, 0);
}

// ---------------------------------------------------------------------------
// prep_all: fuses {ln1, qkv-transpose, w1-transpose, w2-transpose, mask-pack,
// bias-concat} into ONE launch (r6 budget: ~4-5us gap per dispatch x 11).
// Role selected by blockIdx.x range; all roles are input-only + disjoint
// outputs, so一 single launch is safe.
// Block ranges: [0,4096) ln1 | [4096,7168) qkvT | [7168,11264) w1T |
// [11264,15360) w2T | [15360,16384) mask | [16384,16396) concat.
// ---------------------------------------------------------------------------
__global__ __launch_bounds__(256) void prep_all(
    const float* __restrict__ x, const float* __restrict__ ln1g,
    const float* __restrict__ ln1b, unsigned short* __restrict__ h1,
    const float* __restrict__ wq, const float* __restrict__ wk,
    const float* __restrict__ wv, unsigned short* __restrict__ qkvwT,
    const float* __restrict__ w1, unsigned short* __restrict__ w1T,
    const float* __restrict__ w2, unsigned short* __restrict__ w2T,
    const float* __restrict__ dis, const float* __restrict__ cls,
    unsigned short* __restrict__ cmP,
    const float* __restrict__ bq, const float* __restrict__ bk,
    const float* __restrict__ bv, float* __restrict__ qkvb) {
  __shared__ __align__(16) char smraw[16384];
  int bid = blockIdx.x;
  int t = threadIdx.x;
  if (bid < 4096) {
    // ---- ln1: fp32 in, bf16 out ----
    int row = bid;
    float xv[4];
    float4 f4 = *(const float4*)(x + (size_t)row * DD + t * 4);
    xv[0] = f4.x; xv[1] = f4.y; xv[2] = f4.z; xv[3] = f4.w;
    float s1 = xv[0] + xv[1] + xv[2] + xv[3];
    float s2 = xv[0]*xv[0] + xv[1]*xv[1] + xv[2]*xv[2] + xv[3]*xv[3];
#pragma unroll
    for (int off = 32; off > 0; off >>= 1) {
      s1 += __shfl_down(s1, off);
      s2 += __shfl_down(s2, off);
    }
    float* sa = (float*)smraw;
    float* sb = sa + 8;
    int wid = t >> 6;
    if ((t & 63) == 0) { sa[wid] = s1; sb[wid] = s2; }
    __syncthreads();
    s1 = sa[0] + sa[1] + sa[2] + sa[3];
    s2 = sb[0] + sb[1] + sb[2] + sb[3];
    float mean = s1 * (1.0f / 1024.0f);
    float var = s2 * (1.0f / 1024.0f) - mean * mean;
    float rstd = rsqrtf(var + 1e-5f);
    float4 gv = *(const float4*)(ln1g + t * 4);
    float4 bv4 = *(const float4*)(ln1b + t * 4);
    us4 o;
    o[0] = f2bf((xv[0] - mean) * rstd * gv.x + bv4.x);
    o[1] = f2bf((xv[1] - mean) * rstd * gv.y + bv4.y);
    o[2] = f2bf((xv[2] - mean) * rstd * gv.z + bv4.z);
    o[3] = f2bf((xv[3] - mean) * rstd * gv.w + bv4.w);
    *(us4*)(h1 + (size_t)row * DD + t * 4) = o;
  } else if (bid < 4096 + 3072) {
    // ---- qkv weight transpose ----
    int id = bid - 4096;
    int z = id >> 10;
    int rem = id & 1023;
    int bx = rem & 31, by = rem >> 5;
    const float* src = z == 0 ? wq : z == 1 ? wk : wv;
    unsigned short* d = qkvwT + (size_t)z * 1024 * 1024;
    float (*tile)[33] = (float (*)[33])smraw;
    int c = t & 31, rl = t >> 5;
#pragma unroll
    for (int i = 0; i < 4; ++i) {
      int row = rl * 4 + i;
      tile[row][c] = src[(size_t)(by * 32 + row) * DD + bx * 32 + c];
    }
    __syncthreads();
#pragma unroll
    for (int i = 0; i < 4; ++i) {
      int n = rl * 4 + i;
      d[(size_t)(bx * 32 + n) * DD + by * 32 + c] = f2bf(tile[c][n]);
    }
  } else if (bid < 4096 + 3072 + 4096) {
    // ---- w1 transpose: [1024][4096] -> bf16 [4096][1024] ----
    int id = bid - (4096 + 3072);
    int bx = id & 127, by = id >> 7;
    float (*tile)[33] = (float (*)[33])smraw;
    int c = t & 31, rl = t >> 5;
#pragma unroll
    for (int i = 0; i < 4; ++i) {
      int row = rl * 4 + i;
      tile[row][c] = w1[(size_t)(by * 32 + row) * MLPD + bx * 32 + c];
    }
    __syncthreads();
#pragma unroll
    for (int i = 0; i < 4; ++i) {
      int n = rl * 4 + i;
      w1T[(size_t)(bx * 32 + n) * DD + by * 32 + c] = f2bf(tile[c][n]);
    }
  } else if (bid < 4096 + 3072 + 4096 + 4096) {
    // ---- w2 transpose: [4096][1024] -> bf16 [1024][4096] ----
    int id = bid - (4096 + 3072 + 4096);
    int bx = id & 31, by = id >> 5;
    float (*tile)[33] = (float (*)[33])smraw;
    int c = t & 31, rl = t >> 5;
#pragma unroll
    for (int i = 0; i < 4; ++i) {
      int row = rl * 4 + i;
      tile[row][c] = w2[(size_t)(by * 32 + row) * DD + bx * 32 + c];
    }
    __syncthreads();
#pragma unroll
    for (int i = 0; i < 4; ++i) {
      int n = rl * 4 + i;
      w2T[(size_t)(bx * 32 + n) * MLPD + by * 32 + c] = f2bf(tile[c][n]);
    }
  } else if (bid < 4096 + 3072 + 4096 + 4096 + 1024) {
    // ---- mask pack for swapped-QK attn (cmP2 layout):
    // cmP[b][qt16(128)][kt(32)][lane(64)][16];
    // chunk[ta*4+r] = (dis+cls)[qt16*16 + (l&15)][kt*64 + ta*16 + (l>>4)*4 + r] * 8
    int id = bid - (4096 + 3072 + 4096 + 4096);
    int qt16 = id & 127, ktg = (id >> 7) & 3, b = id >> 9;
    unsigned short (*sm)[512] = (unsigned short (*)[512])smraw;
    int row0 = qt16 * 16, col0 = ktg * 512;
    const float* db = dis + (size_t)b * SS * SS;
    const float* cb = cls + (size_t)b * SS * SS;
    int lrow = t >> 4, lcg = t & 15;
#pragma unroll
    for (int shot = 0; shot < 8; ++shot) {
      int cc = lcg * 4 + shot * 64;
      size_t idx = (size_t)(row0 + lrow) * SS + col0 + cc;
      float4 d4 = *(const float4*)(db + idx);
      float4 c4 = *(const float4*)(cb + idx);
      us4 o;
      o[0] = f2bf((d4.x + c4.x) * 8.0f);
      o[1] = f2bf((d4.y + c4.y) * 8.0f);
      o[2] = f2bf((d4.z + c4.z) * 8.0f);
      o[3] = f2bf((d4.w + c4.w) * 8.0f);
      *(us4*)&sm[lrow][cc] = o;
    }
    __syncthreads();
    int ktL = t >> 5, lp = t & 31;
    unsigned short* ob =
        cmP + (((size_t)(b * 128 + qt16) * 32 + ktg * 8 + ktL) * 64) * 16;
#pragma unroll
    for (int li = 0; li < 2; ++li) {
      int l = lp * 2 + li;
      int g = l >> 4, c16 = l & 15;
      short vv[16];
#pragma unroll
      for (int ta = 0; ta < 4; ++ta)
#pragma unroll
        for (int r = 0; r < 4; ++r)
          vv[ta * 4 + r] = (short)sm[c16][ktL * 64 + ta * 16 + g * 4 + r];
      unsigned short* o = ob + (size_t)l * 16;
      *(bf16x8*)(o) = *(bf16x8*)&vv[0];
      *(bf16x8*)(o + 8) = *(bf16x8*)&vv[8];
    }
  } else {
    // ---- bias concat ----
    int id = bid - (4096 + 3072 + 4096 + 4096 + 1024);
    int i = id * 256 + t;
    if (i < 1024) qkvb[i] = bq[i];
    else if (i < 2048) qkvb[i] = bk[i - 1024];
    else if (i < 3072) qkvb[i] = bv[i - 2048];
  }
}

// ---------------------------------------------------------------------------
// LayerNorm -> bf16 out (kept for ln2)
// ---------------------------------------------------------------------------
template <bool BF_IN, bool ADD>
__global__ __launch_bounds__(256) void ln_bf16(
    const void* __restrict__ in, const float* __restrict__ add,
    const float* __restrict__ g, const float* __restrict__ beta,
    unsigned short* __restrict__ out) {
  int row = blockIdx.x;
  int t = threadIdx.x;
  float x[4];
  if (BF_IN) {
    us4 b4 = *(const us4*)((const unsigned short*)in + (size_t)row * DD + t * 4);
#pragma unroll
    for (int i = 0; i < 4; ++i) x[i] = bf2f(b4[i]);
  } else {
    float4 f4 = *(const float4*)((const float*)in + (size_t)row * DD + t * 4);
    x[0] = f4.x; x[1] = f4.y; x[2] = f4.z; x[3] = f4.w;
  }
  if (ADD) {
    float4 a4 = *(const float4*)(add + (size_t)row * DD + t * 4);
    x[0] += a4.x; x[1] += a4.y; x[2] += a4.z; x[3] += a4.w;
  }
  float s1 = x[0] + x[1] + x[2] + x[3];
  float s2 = x[0] * x[0] + x[1] * x[1] + x[2] * x[2] + x[3] * x[3];
#pragma unroll
  for (int off = 32; off > 0; off >>= 1) {
    s1 += __shfl_down(s1, off);
    s2 += __shfl_down(s2, off);
  }
  __shared__ float sa[4], sb[4];
  int wid = t >> 6;
  if ((t & 63) == 0) { sa[wid] = s1; sb[wid] = s2; }
  __syncthreads();
  s1 = sa[0] + sa[1] + sa[2] + sa[3];
  s2 = sb[0] + sb[1] + sb[2] + sb[3];
  float mean = s1 * (1.0f / 1024.0f);
  float var = s2 * (1.0f / 1024.0f) - mean * mean;
  float rstd = rsqrtf(var + 1e-5f);
  float4 gv = *(const float4*)(g + t * 4);
  float4 bv = *(const float4*)(beta + t * 4);
  us4 o;
  o[0] = f2bf((x[0] - mean) * rstd * gv.x + bv.x);
  o[1] = f2bf((x[1] - mean) * rstd * gv.y + bv.y);
  o[2] = f2bf((x[2] - mean) * rstd * gv.z + bv.z);
  o[3] = f2bf((x[3] - mean) * rstd * gv.w + bv.w);
  *(us4*)(out + (size_t)row * DD + t * 4) = o;
}

// ---------------------------------------------------------------------------
// Legacy bf16 MFMA GEMM (128xBN tile) for MLP2 (N=1024), with XCD swizzle.
// ---------------------------------------------------------------------------
template <int BN, bool GELU, bool ADDSRC, bool OUT_BF16, bool SPLIT3>
__global__ __launch_bounds__(256) void gemm_bf16(
    const unsigned short* __restrict__ A, const unsigned short* __restrict__ BT,
    const float* __restrict__ bias, const unsigned short* __restrict__ addsrc,
    void* C0, void* C1, void* C2, int M, int N, int K) {
  constexpr int BJ = BN / 32;
  constexpr int BCH = BN / 64;
  __shared__ __align__(16) unsigned short As[128][32];
  __shared__ __align__(16) unsigned short Bs[BN][32];
  int tid = threadIdx.x;
  int wave = tid >> 6, lane = tid & 63;
  int g = lane >> 4, c16 = lane & 15;
  int nwg = gridDim.x * gridDim.y;
  int wg = blockIdx.y * gridDim.x + blockIdx.x;
  int cpx = nwg >> 3;
  int sw = (wg & 7) * cpx + (wg >> 3);
  int bxs = sw % gridDim.x, bys = sw / gridDim.x;
  int m0 = bys * 128, n0 = bxs * BN;
  int wm = (wave >> 1) * 64, wn = (wave & 1) * (BN / 2);
  int lrow = lane >> 2, lq = lane & 3;
  int dq = (lq ^ swz(lrow)) * 8;
  const unsigned short* aS = A + (size_t)(m0 + wave * 32 + lrow) * K + lq * 8;
  unsigned short* aD0 = &As[wave * 32 + lrow][dq];
  unsigned short* aD1 = &As[wave * 32 + 16 + lrow][dq];
  const unsigned short* bS = BT + (size_t)(n0 + wave * (BCH * 16) + lrow) * K + lq * 8;
  unsigned short* bD0 = &Bs[wave * (BCH * 16) + lrow][dq];
  unsigned short* bD1 = &Bs[(wave * (BCH * 16) + 16 + lrow) % BN][dq];
  int vA = (g ^ swz(c16)) * 8;
  const int KI = K / 32;
  const size_t rK = 16 * (size_t)K;

  bf16x8 a0a = *(const bf16x8*)(aS);
  bf16x8 a1a = *(const bf16x8*)(aS + rK);
  bf16x8 b0a = *(const bf16x8*)(bS);
  bf16x8 b1a;
  if constexpr (BCH == 2) b1a = *(const bf16x8*)(bS + rK);
  bf16x8 a0b = *(const bf16x8*)(aS + 32);
  bf16x8 a1b = *(const bf16x8*)(aS + rK + 32);
  bf16x8 b0b = *(const bf16x8*)(bS + 32);
  bf16x8 b1b;
  if constexpr (BCH == 2) b1b = *(const bf16x8*)(bS + rK + 32);

  f32x4 acc[4][BJ] = {};
  for (int kt = 0; kt < KI; kt += 2) {
    __syncthreads();
    *(bf16x8*)aD0 = a0a;
    *(bf16x8*)aD1 = a1a;
    *(bf16x8*)bD0 = b0a;
    if constexpr (BCH == 2) *(bf16x8*)bD1 = b1a;
    __syncthreads();
    if (kt + 2 < KI) {
      int ko = (kt + 2) * 32;
      a0a = *(const bf16x8*)(aS + ko);
      a1a = *(const bf16x8*)(aS + rK + ko);
      b0a = *(const bf16x8*)(bS + ko);
      if constexpr (BCH == 2) b1a = *(const bf16x8*)(bS + rK + ko);
    }
    {
      bf16x8 a[4], b[BJ];
#pragma unroll
      for (int i = 0; i < 4; ++i) a[i] = *(const bf16x8*)&As[wm + i * 16 + c16][vA];
#pragma unroll
      for (int j = 0; j < BJ; ++j) b[j] = *(const bf16x8*)&Bs[wn + j * 16 + c16][vA];
#pragma unroll
      for (int i = 0; i < 4; ++i)
#pragma unroll
        for (int j = 0; j < BJ; ++j)
          acc[i][j] = __builtin_amdgcn_mfma_f32_16x16x32_bf16(a[i], b[j], acc[i][j], 0, 0, 0);
    }
    __syncthreads();
    *(bf16x8*)aD0 = a0b;
    *(bf16x8*)aD1 = a1b;
    *(bf16x8*)bD0 = b0b;
    if constexpr (BCH == 2) *(bf16x8*)bD1 = b1b;
    __syncthreads();
    if (kt + 3 < KI) {
      int ko = (kt + 3) * 32;
      a0b = *(const bf16x8*)(aS + ko);
      a1b = *(const bf16x8*)(aS + rK + ko);
      b0b = *(const bf16x8*)(bS + ko);
      if constexpr (BCH == 2) b1b = *(const bf16x8*)(bS + rK + ko);
    }
    {
      bf16x8 a[4], b[BJ];
#pragma unroll
      for (int i = 0; i < 4; ++i) a[i] = *(const bf16x8*)&As[wm + i * 16 + c16][vA];
#pragma unroll
      for (int j = 0; j < BJ; ++j) b[j] = *(const bf16x8*)&Bs[wn + j * 16 + c16][vA];
#pragma unroll
      for (int i = 0; i < 4; ++i)
#pragma unroll
        for (int j = 0; j < BJ; ++j)
          acc[i][j] = __builtin_amdgcn_mfma_f32_16x16x32_bf16(a[i], b[j], acc[i][j], 0, 0, 0);
    }
  }
  unsigned short* dstb = nullptr;
  int lc0 = 0;
  if (SPLIT3) {
    int which = n0 >> 10;
    dstb = (unsigned short*)(which == 0 ? C0 : which == 1 ? C1 : C2);
    lc0 = n0 & 1023;
  }
#pragma unroll
  for (int j = 0; j < BJ; ++j) {
    int coff = wn + j * 16 + c16;
    float bj = bias[n0 + coff];
#pragma unroll
    for (int i = 0; i < 4; ++i) {
#pragma unroll
      for (int r = 0; r < 4; ++r) {
        int row = m0 + wm + i * 16 + g * 4 + r;
        float cval = acc[i][j][r] + bj;
        if (GELU) cval = gelu_f(cval);
        if (ADDSRC) cval += bf2f(addsrc[(size_t)row * N + n0 + coff]);
        if (SPLIT3) {
          dstb[(size_t)row * 1024 + lc0 + coff] = f2bf(cval);
        } else if (OUT_BF16) {
          ((unsigned short*)C0)[(size_t)row * N + n0 + coff] = f2bf(cval);
        } else {
          ((float*)C0)[(size_t)row * N + n0 + coff] = cval;
        }
      }
    }
  }
}

// ---------------------------------------------------------------------------
// 256x256 8-phase bf16 GEMM v3 (snake + reg reuse + derived vmcnt + XCD swz).
// ---------------------------------------------------------------------------
#define VMW(n) asm volatile("s_waitcnt vmcnt(" #n ")" ::: "memory")
#define BARX() do { asm volatile("" ::: "memory"); \
                    __builtin_amdgcn_s_barrier(); \
                    asm volatile("" ::: "memory"); } while (0)

template <bool GELU, bool SPLIT3>
__global__ __launch_bounds__(512, 2) void gemm256(
    const unsigned short* __restrict__ A, const unsigned short* __restrict__ BT,
    const float* __restrict__ bias, void* C0, void* C1, void* C2,
    int N, int K) {
  __shared__ __align__(16) char lds[2][2][2][16384];
  int tid = threadIdx.x;
  int lane = tid & 63, w = tid >> 6;
  int g = lane >> 4, c16 = lane & 15;
  int wm16 = (w >> 2) << 4;
  int wn16 = (w & 3) << 4;
  int nwg = gridDim.x * gridDim.y;
  int wg = blockIdx.y * gridDim.x + blockIdx.x;
  int cpx = nwg >> 3;
  int sw = (wg & 7) * cpx + (wg >> 3);
  int bx = sw % gridDim.x, by = sw / gridDim.x;
  int m0 = by << 8, n0 = bx << 8;

  int st0 = tid >> 6, ci0 = tid & 63;
  int cp0 = ci0 ^ (((ci0 >> 5) & 1) << 1);
  int sr0 = ((st0 >> 1) << 4) + (cp0 >> 2);
  int sk0 = ((st0 & 1) << 5) + ((cp0 & 3) << 3);
  size_t soff = (size_t)sr0 * K + sk0;

  auto stage = [&](int op, int h, int tt, int d) {
    const unsigned short* base = (op == 0 ? A : BT);
    int row0 = (op == 0 ? m0 : n0) + (h << 7);
    const unsigned short* src = base + (size_t)row0 * K + (tt << 6) + soff;
    unsigned short* dst = (unsigned short*)&lds[op][d][h][tid * 16];
    async16(src, dst);
    async16(src + ((size_t)K << 6), dst + 4096);
  };

  auto foff = [&](int r, int ke) -> int {
    int stt = ((r >> 4) << 1) + (ke >> 5);
    int loc = ((r & 15) << 6) + ((ke & 31) << 1);
    return (stt << 10) + (loc ^ (((r >> 3) & 1) << 5));
  };
  int offA[4][2], offB[2][2];
#pragma unroll
  for (int ii = 0; ii < 4; ++ii)
#pragma unroll
    for (int ks = 0; ks < 2; ++ks)
      offA[ii][ks] = foff(ii * 32 + wm16 + c16, ks * 32 + g * 8);
#pragma unroll
  for (int jj = 0; jj < 2; ++jj)
#pragma unroll
    for (int ks = 0; ks < 2; ++ks)
      offB[jj][ks] = foff(jj * 64 + wn16 + c16, ks * 32 + g * 8);

  f32x4 acc[8][4] = {};

#define MFMA_Q(IH, JH, AF, BF) do {                                           \
    __builtin_amdgcn_s_setprio(1);                                            \
    _Pragma("unroll") for (int ii = 0; ii < 4; ++ii)                          \
      _Pragma("unroll") for (int jj = 0; jj < 2; ++jj) {                      \
        acc[(IH)*4+ii][(JH)*2+jj] = __builtin_amdgcn_mfma_f32_16x16x32_bf16(  \
            AF[ii][0], BF[jj][0], acc[(IH)*4+ii][(JH)*2+jj], 0, 0, 0);        \
        acc[(IH)*4+ii][(JH)*2+jj] = __builtin_amdgcn_mfma_f32_16x16x32_bf16(  \
            AF[ii][1], BF[jj][1], acc[(IH)*4+ii][(JH)*2+jj], 0, 0, 0);        \
      }                                                                       \
    __builtin_amdgcn_s_setprio(0);                                            \
  } while (0)

  stage(0, 0, 0, 0);
  stage(1, 0, 0, 0);
  stage(0, 1, 0, 0);
  stage(1, 1, 0, 0);
  VMW(4);
  BARX();

  const int KT = K >> 6;
  for (int kt = 0; kt < KT; ++kt) {
    int d = kt & 1, dn = d ^ 1;
    int t1 = kt + 1 < KT ? kt + 1 : KT - 1;
    const char* pd = &lds[0][d][0][0];
    bf16x8 A0f[4][2], A1f[4][2], Bf[2][2];

#pragma unroll
    for (int ii = 0; ii < 4; ++ii)
#pragma unroll
      for (int ks = 0; ks < 2; ++ks)
        A0f[ii][ks] = *(const bf16x8*)(pd + offA[ii][ks]);
#pragma unroll
    for (int jj = 0; jj < 2; ++jj)
#pragma unroll
      for (int ks = 0; ks < 2; ++ks)
        Bf[jj][ks] = *(const bf16x8*)(pd + 65536 + offB[jj][ks]);
    stage(0, 0, t1, dn);
    stage(1, 0, t1, dn);
    VMW(6);
    BARX();
    MFMA_Q(0, 0, A0f, Bf);
    BARX();

#pragma unroll
    for (int ii = 0; ii < 4; ++ii)
#pragma unroll
      for (int ks = 0; ks < 2; ++ks)
        A1f[ii][ks] = *(const bf16x8*)(pd + 16384 + offA[ii][ks]);
    stage(0, 1, t1, dn);
    VMW(6);
    BARX();
    MFMA_Q(1, 0, A1f, Bf);
    BARX();

#pragma unroll
    for (int jj = 0; jj < 2; ++jj)
#pragma unroll
      for (int ks = 0; ks < 2; ++ks)
        Bf[jj][ks] = *(const bf16x8*)(pd + 81920 + offB[jj][ks]);
    stage(1, 1, t1, dn);
    BARX();
    MFMA_Q(1, 1, A1f, Bf);
    BARX();

    VMW(4);
    BARX();
    MFMA_Q(0, 1, A0f, Bf);
    BARX();
  }
#undef MFMA_Q
  VMW(0);

  unsigned short* dstb = nullptr;
  int lc0 = 0;
  if (SPLIT3) {
    int which = n0 >> 10;
    dstb = (unsigned short*)(which == 0 ? C0 : which == 1 ? C1 : C2);
    lc0 = n0 & 1023;
  }
#pragma unroll
  for (int i = 0; i < 8; ++i) {
#pragma unroll
    for (int j = 0; j < 4; ++j) {
      int row_b = m0 + ((i >> 2) << 7) + ((i & 3) << 5) + wm16 + (g << 2);
      int colp = ((j >> 1) << 7) + ((j & 1) << 6) + wn16 + c16;
      float bj = bias[n0 + colp];
#pragma unroll
      for (int r = 0; r < 4; ++r) {
        float cv = acc[i][j][r] + bj;
        if (GELU) cv = gelu_f(cv);
        int row = row_b + r;
        if (SPLIT3) {
          dstb[(size_t)row * 1024 + lc0 + colp] = f2bf(cv);
        } else {
          ((unsigned short*)C0)[(size_t)row * N + n0 + colp] = f2bf(cv);
        }
      }
    }
  }
}

// ---------------------------------------------------------------------------
// MFMA flash attention v7: swapped QK^T + in-register P + permuted-V.
//  - s' = mfma(K_frag, Q_frag): accumulator has q LANE-LOCAL (lane&15 = q),
//    keys on regs [ta(0..3) x r(0..3)] => P never touches LDS.
//  - mask pre-packed in this swapped C-layout initializes the accumulator.
//  - P packed to bf16 in-register feeds PV as the B-operand directly; V is
//    staged with permuted key-columns c(key)=(key&0x20)|((key&0xC)<<1)|
//    ((key&0x10)>>2)|(key&3) so MFMA k-slot kk holds key sigma(ks,kk) on BOTH
//    operands (k-slot permutation is dot-product-invariant when consistent).
//  - output O[vd][q] per lane => transposed us4 row-writes.
// 256 thr / 4 waves; 128 q-rows/block (wave: 2 subtiles of 16);
// grid (h,qt,b) => wgid%8 = h%8: head-affine XCD (K/V L2-resident, 2MB/XCD).
// LDS/wave/kt: 309cyc (was 543) -> per-CU floor ~33us.
// ---------------------------------------------------------------------------
__global__ __launch_bounds__(256) void attn_mfma7(
    const unsigned short* __restrict__ q, const unsigned short* __restrict__ k,
    const unsigned short* __restrict__ v, const unsigned short* __restrict__ cmP,
    unsigned short* __restrict__ outO) {
  __shared__ __align__(16) unsigned short Ks[2][64][32];
  __shared__ __align__(16) unsigned short Vt[64][72];
  int tid = threadIdx.x;
  int wave = tid >> 6, lane = tid & 63;
  int g = lane >> 4, c16 = lane & 15;
  int h = blockIdx.x, qt = blockIdx.y, b = blockIdx.z;
  int qbA = qt * 128 + wave * 32;
  int qbB = qbA + 16;
  size_t headoff = (size_t)b * SS * DD + (size_t)h * SS * 64;
  const unsigned short* qp = q + headoff;
  const unsigned short* kb = k + headoff;
  const unsigned short* vb = v + headoff;
  // cmP2[b][qt16][kt][lane][16]
  int qt16A = qbA >> 4;
  const unsigned short* csrcA =
      cmP + (((size_t)(b * 128 + qt16A) * 32 * 64) + lane) * 16;
  const unsigned short* csrcB = csrcA + 32 * 64 * 16;

  // K staging: thread -> key row kkey, two 8-elem d-segs
  int kkey = tid >> 2, lq2 = tid & 3;
  int ksg0 = lq2 * 2, ksg1 = ksg0 + 1;
  unsigned short* kdst0 = &Ks[ksg0 >> 2][kkey][((ksg0 & 3) ^ swz(kkey)) * 8];
  unsigned short* kdst1 = &Ks[ksg1 >> 2][kkey][((ksg1 & 3) ^ swz(kkey)) * 8];
  const unsigned short* ksrc = kb + (size_t)kkey * 64 + ksg0 * 8;

  // V staging: key = lane, vd section = wave*16; column permuted by c(key)
  int vcol = (lane & 0x20) | ((lane & 0x0C) << 1) | ((lane & 0x10) >> 2) | (lane & 3);
  const unsigned short* vsrc = vb + (size_t)lane * 64 + wave * 16;
  int vK = (g ^ swz(c16)) * 8;

  bf16x8 qf0A = *(const bf16x8*)(qp + (size_t)(qbA + c16) * 64 + g * 8);
  bf16x8 qf1A = *(const bf16x8*)(qp + (size_t)(qbA + c16) * 64 + 32 + g * 8);
  bf16x8 qf0B = *(const bf16x8*)(qp + (size_t)(qbB + c16) * 64 + g * 8);
  bf16x8 qf1B = *(const bf16x8*)(qp + (size_t)(qbB + c16) * 64 + 32 + g * 8);
  bf16x8 ones;
#pragma unroll
  for (int j = 0; j < 8; ++j) ones[j] = (short)0x3F80;
  f32x4 oA[4] = {}, oB[4] = {};
  f32x4 olA = {}, olB = {};
  const float scale2 = 0.18033688f;  // 0.125*log2(e)

  bf16x8 kregA = *(const bf16x8*)(ksrc);
  bf16x8 kregB = *(const bf16x8*)(ksrc + 8);
  bf16x8 vregA = *(const bf16x8*)(vsrc);
  bf16x8 vregB = *(const bf16x8*)(vsrc + 8);
  bf16x8 cmA0 = *(const bf16x8*)(csrcA);
  bf16x8 cmA1 = *(const bf16x8*)(csrcA + 8);
  bf16x8 cmB0 = *(const bf16x8*)(csrcB);
  bf16x8 cmB1 = *(const bf16x8*)(csrcB + 8);

  for (int kt = 0; kt < 32; ++kt) {
    __syncthreads();
    *(bf16x8*)kdst0 = kregA;
    *(bf16x8*)kdst1 = kregB;
#pragma unroll
    for (int j = 0; j < 8; ++j) {
      Vt[wave * 16 + j][vcol] = (unsigned short)vregA[j];
      Vt[wave * 16 + 8 + j][vcol] = (unsigned short)vregB[j];
    }
    __syncthreads();

    int ktn = kt + 1 < 32 ? kt + 1 : 31;
    bf16x8 kregAN = *(const bf16x8*)(ksrc + (size_t)ktn * 4096);
    bf16x8 kregBN = *(const bf16x8*)(ksrc + (size_t)ktn * 4096 + 8);
    bf16x8 vregAN = *(const bf16x8*)(vsrc + (size_t)ktn * 4096);
    bf16x8 vregBN = *(const bf16x8*)(vsrc + (size_t)ktn * 4096 + 8);
    bf16x8 cmA0N = *(const bf16x8*)(csrcA + (size_t)ktn * 1024);
    bf16x8 cmA1N = *(const bf16x8*)(csrcA + (size_t)ktn * 1024 + 8);
    bf16x8 cmB0N = *(const bf16x8*)(csrcB + (size_t)ktn * 1024);
    bf16x8 cmB1N = *(const bf16x8*)(csrcB + (size_t)ktn * 1024 + 8);

    // swapped QK^T: acc init = mask*8 in C[key(reg)][q(lane)] layout
    f32x4 sA[4], sB[4];
#pragma unroll
    for (int r = 0; r < 4; ++r) {
      sA[0][r] = bf2f((unsigned short)cmA0[r]);
      sA[1][r] = bf2f((unsigned short)cmA0[4 + r]);
      sA[2][r] = bf2f((unsigned short)cmA1[r]);
      sA[3][r] = bf2f((unsigned short)cmA1[4 + r]);
      sB[0][r] = bf2f((unsigned short)cmB0[r]);
      sB[1][r] = bf2f((unsigned short)cmB0[4 + r]);
      sB[2][r] = bf2f((unsigned short)cmB1[r]);
      sB[3][r] = bf2f((unsigned short)cmB1[4 + r]);
    }
#pragma unroll
    for (int ta = 0; ta < 4; ++ta) {
      bf16x8 kf0 = *(const bf16x8*)&Ks[0][ta * 16 + c16][vK];
      bf16x8 kf1 = *(const bf16x8*)&Ks[1][ta * 16 + c16][vK];
      sA[ta] = __builtin_amdgcn_mfma_f32_16x16x32_bf16(kf0, qf0A, sA[ta], 0, 0, 0);
      sA[ta] = __builtin_amdgcn_mfma_f32_16x16x32_bf16(kf1, qf1A, sA[ta], 0, 0, 0);
      sB[ta] = __builtin_amdgcn_mfma_f32_16x16x32_bf16(kf0, qf0B, sB[ta], 0, 0, 0);
      sB[ta] = __builtin_amdgcn_mfma_f32_16x16x32_bf16(kf1, qf1B, sB[ta], 0, 0, 0);
    }
    // exp in-register; pack to bf16 B-frags (slot jj -> key held in reg:
    // eX[8ks + jj] = P[q][key 16*(2ks+(jj>>2)) + 4g + (jj&3)] = sigma-order)
    float eA[16], eB[16];
#pragma unroll
    for (int ta = 0; ta < 4; ++ta)
#pragma unroll
      for (int r = 0; r < 4; ++r) {
        eA[ta * 4 + r] = fast_exp2(sA[ta][r] * scale2);
        eB[ta * 4 + r] = fast_exp2(sB[ta][r] * scale2);
      }
    bf16x8 pbA[2], pbB[2];
#pragma unroll
    for (int ks = 0; ks < 2; ++ks) {
      union { unsigned int w[4]; bf16x8 v8; } ua, ub;
      ua.w[0] = packbf(eA[8 * ks + 0], eA[8 * ks + 1]);
      ua.w[1] = packbf(eA[8 * ks + 2], eA[8 * ks + 3]);
      ua.w[2] = packbf(eA[8 * ks + 4], eA[8 * ks + 5]);
      ua.w[3] = packbf(eA[8 * ks + 6], eA[8 * ks + 7]);
      ub.w[0] = packbf(eB[8 * ks + 0], eB[8 * ks + 1]);
      ub.w[1] = packbf(eB[8 * ks + 2], eB[8 * ks + 3]);
      ub.w[2] = packbf(eB[8 * ks + 4], eB[8 * ks + 5]);
      ub.w[3] = packbf(eB[8 * ks + 6], eB[8 * ks + 7]);
      pbA[ks] = ua.v8;
      pbB[ks] = ub.v8;
    }
    // PV: A = permuted-V frags, B = in-register P; O[vd(reg)][q(lane)]
#pragma unroll
    for (int ks = 0; ks < 2; ++ks) {
#pragma unroll
      for (int t2 = 0; t2 < 4; ++t2) {
        bf16x8 vb8 = *(const bf16x8*)&Vt[t2 * 16 + c16][ks * 32 + g * 8];
        oA[t2] = __builtin_amdgcn_mfma_f32_16x16x32_bf16(vb8, pbA[ks], oA[t2], 0, 0, 0);
        oB[t2] = __builtin_amdgcn_mfma_f32_16x16x32_bf16(vb8, pbB[ks], oB[t2], 0, 0, 0);
      }
      olA = __builtin_amdgcn_mfma_f32_16x16x32_bf16(ones, pbA[ks], olA, 0, 0, 0);
      olB = __builtin_amdgcn_mfma_f32_16x16x32_bf16(ones, pbB[ks], olB, 0, 0, 0);
    }
    kregA = kregAN; kregB = kregBN;
    vregA = vregAN; vregB = vregBN;
    cmA0 = cmA0N; cmA1 = cmA1N;
    cmB0 = cmB0N; cmB1 = cmB1N;
  }
  float invA = fast_rcp(olA[0]);
  float invB = fast_rcp(olB[0]);
#pragma unroll
  for (int t2 = 0; t2 < 4; ++t2) {
    us4 wA, wB;
#pragma unroll
    for (int r = 0; r < 4; ++r) {
      wA[r] = f2bf(oA[t2][r] * invA);
      wB[r] = f2bf(oB[t2][r] * invB);
    }
    *(us4*)(outO + headoff + (size_t)(qbA + c16) * 64 + t2 * 16 + g * 4) = wA;
    *(us4*)(outO + headoff + (size_t)(qbB + c16) * 64 + t2 * 16 + g * 4) = wB;
  }
}

// ---------------------------------------------------------------------------
extern "C" void kernel_launch(void* const* d_in, const int* in_sizes, int n_in,
                              void* d_out, int out_size, void* d_ws, size_t ws_size,
                              hipStream_t stream) {
  const float* x    = (const float*)d_in[0];
  const float* dis  = (const float*)d_in[1];
  const float* cls  = (const float*)d_in[2];
  const float* wq   = (const float*)d_in[3];
  const float* bq   = (const float*)d_in[4];
  const float* wk   = (const float*)d_in[5];
  const float* bk   = (const float*)d_in[6];
  const float* wv   = (const float*)d_in[7];
  const float* bv   = (const float*)d_in[8];
  const float* ln1g = (const float*)d_in[9];
  const float* ln1b = (const float*)d_in[10];
  const float* ln2g = (const float*)d_in[11];
  const float* ln2b = (const float*)d_in[12];
  const float* w1   = (const float*)d_in[13];
  const float* b1   = (const float*)d_in[14];
  const float* w2   = (const float*)d_in[15];
  const float* b2   = (const float*)d_in[16];
  float* out = (float*)d_out;
  char* ws = (char*)d_ws;

  unsigned short* qkvwT = (unsigned short*)(ws + 0);           // 6 MB
  unsigned short* w1T   = (unsigned short*)(ws + 6291456);     // 8 MB
  unsigned short* w2T   = (unsigned short*)(ws + 14680064);    // 8 MB
  float*          qkvb  = (float*)(ws + 23068672);             // 12 KB
  unsigned short* r1    = (unsigned short*)(ws + 23134208);    // 8 MB: h1 -> attnO
  unsigned short* qbuf  = (unsigned short*)(ws + 31522816);    // 8 MB
  unsigned short* kbuf  = (unsigned short*)(ws + 39911424);    // 8 MB
  unsigned short* vbuf  = (unsigned short*)(ws + 48300032);    // 8 MB
  unsigned short* h2    = (unsigned short*)(ws + 56688640);    // 8 MB
  unsigned short* cmP   = (unsigned short*)(ws + 65077248);    // 16.78 MB
  unsigned short* mm    = (unsigned short*)(ws + 23134208);    // 32 MB overlays r1/q/k/v
  unsigned short* h1 = r1;
  unsigned short* attnO = r1;

  const int rows = BB * SS;  // 4096

  // all prep (ln1, 3 transposes, mask-pack, bias-concat) in ONE launch
  prep_all<<<16396, 256, 0, stream>>>(
      x, ln1g, ln1b, h1, wq, wk, wv, qkvwT, w1, w1T, w2, w2T,
      dis, cls, cmP, bq, bk, bv, qkvb);

  // QKV: 256x256 8-phase v3, SPLIT3 epilogue (192 blocks)
  gemm256<false, true><<<dim3(3072 / 256, rows / 256), 512, 0, stream>>>(
      h1, qkvwT, qkvb, qbuf, kbuf, vbuf, 3072, DD);

  // attn v7: swapped-QK in-register-P; grid h-major => head-affine XCD
  attn_mfma7<<<dim3(HH, SS / 128, BB), 256, 0, stream>>>(
      qbuf, kbuf, vbuf, cmP, attnO);

  ln_bf16<true, true><<<rows, 256, 0, stream>>>(attnO, x, ln2g, ln2b, h2);

  // MLP1: 256x256 8-phase v3 + GELU (256 blocks)
  gemm256<true, false><<<dim3(MLPD / 256, rows / 256), 512, 0, stream>>>(
      h2, w1T, b1, mm, nullptr, nullptr, MLPD, DD);

  // MLP2 (N=1024): legacy 128x64 path + XCD swizzle
  gemm_bf16<64, false, true, false, false><<<dim3(DD / 64, rows / 128), 256, 0, stream>>>(
      mm, w2T, b2, h2, out, nullptr, nullptr, rows, DD, MLPD);
}